// Round 3
// baseline (703.244 us; speedup 1.0000x reference)
//
#include <hip/hip_runtime.h>
#include <math.h>

#define D 256
#define WDECAY 1e-6f
#define CHUNK 1024   // elements per scan block (256 threads x 4)

// ---------------- CSR build ----------------

__global__ __launch_bounds__(256) void hist_kernel(
    const int* __restrict__ src, const int* __restrict__ dst, int E,
    int* __restrict__ cnt)
{
    int i = blockIdx.x * blockDim.x + threadIdx.x;
    if (i < 2 * E) {
        int n = (i < E) ? src[i] : dst[i - E];
        atomicAdd(&cnt[n], 1);
    }
}

__global__ __launch_bounds__(256) void scan_partial(
    const int* __restrict__ cnt, int N, int* __restrict__ bsum)
{
    __shared__ int sdata[256];
    int b = blockIdx.x, t = threadIdx.x;
    int base = b * CHUNK + 4 * t;
    int s = 0;
    if (base + 3 < N) {
        int4 v = *(const int4*)(cnt + base);
        s = v.x + v.y + v.z + v.w;
    } else {
        for (int k = 0; k < 4; ++k)
            if (base + k < N) s += cnt[base + k];
    }
    sdata[t] = s;
    __syncthreads();
    for (int off = 128; off > 0; off >>= 1) {
        if (t < off) sdata[t] += sdata[t + off];
        __syncthreads();
    }
    if (t == 0) bsum[b] = sdata[0];
}

__global__ __launch_bounds__(256) void scan_blocksums(
    int* __restrict__ bsum, int NB, int* __restrict__ row_start, int N)
{
    __shared__ int part[256];
    int t = threadIdx.x;
    int per = (NB + 255) / 256;
    int lo = t * per, hi = lo + per;
    if (hi > NB) hi = NB;
    int s = 0;
    for (int i = lo; i < hi; ++i) s += bsum[i];
    part[t] = s;
    __syncthreads();
    for (int off = 1; off < 256; off <<= 1) {
        int v = (t >= off) ? part[t - off] : 0;
        __syncthreads();
        part[t] += v;
        __syncthreads();
    }
    int base = (t == 0) ? 0 : part[t - 1];
    for (int i = lo; i < hi; ++i) {
        int c = bsum[i];
        bsum[i] = base;
        base += c;
    }
    if (t == 255) row_start[N] = part[255];
}

__global__ __launch_bounds__(256) void scan_apply(
    int* __restrict__ cnt, const int* __restrict__ bsum,
    int* __restrict__ row_start, int N)
{
    __shared__ int part[256];
    int b = blockIdx.x, t = threadIdx.x;
    int base = b * CHUNK + 4 * t;
    int4 v = make_int4(0, 0, 0, 0);
    if (base + 3 < N) {
        v = *(const int4*)(cnt + base);
    } else {
        if (base + 0 < N) v.x = cnt[base + 0];
        if (base + 1 < N) v.y = cnt[base + 1];
        if (base + 2 < N) v.z = cnt[base + 2];
    }
    part[t] = v.x + v.y + v.z + v.w;
    __syncthreads();
    for (int off = 1; off < 256; off <<= 1) {
        int pv = (t >= off) ? part[t - off] : 0;
        __syncthreads();
        part[t] += pv;
        __syncthreads();
    }
    int p = bsum[b] + ((t == 0) ? 0 : part[t - 1]);
    int p0 = p, p1 = p0 + v.x, p2 = p1 + v.y, p3 = p2 + v.z;
    if (base + 0 < N) { row_start[base + 0] = p0; cnt[base + 0] = p0; }
    if (base + 1 < N) { row_start[base + 1] = p1; cnt[base + 1] = p1; }
    if (base + 2 < N) { row_start[base + 2] = p2; cnt[base + 2] = p2; }
    if (base + 3 < N) { row_start[base + 3] = p3; cnt[base + 3] = p3; }
}

__global__ __launch_bounds__(256) void fill_kernel(
    const int* __restrict__ src, const int* __restrict__ dst,
    const float* __restrict__ times, int E,
    int* __restrict__ cursor, int* __restrict__ adj_other,
    float* __restrict__ adj_tw)
{
    int i = blockIdx.x * blockDim.x + threadIdx.x;
    if (i >= 2 * E) return;
    int e = (i < E) ? i : i - E;
    int node  = (i < E) ? src[e] : dst[e];
    int other = (i < E) ? dst[e] : src[e];
    float tlast = times[E - 1];
    float w = expf(-WDECAY * (tlast - times[e]));
    int pos = atomicAdd(&cursor[node], 1);
    adj_other[pos] = other;
    adj_tw[pos] = w;
}

// Mark nodes that appear in any query pair.
__global__ __launch_bounds__(256) void set_flags(
    const int* __restrict__ qs, const int* __restrict__ qd, int B,
    int* __restrict__ flag)
{
    int i = blockIdx.x * blockDim.x + threadIdx.x;
    if (i < B) {
        flag[qs[i]] = 1;
        flag[qd[i]] = 1;
    }
}

// Transpose w1 [64][256] -> w1t [256][64] so MLP weight rows are contiguous.
__global__ __launch_bounds__(256) void transpose_w1(
    const float* __restrict__ w1, float* __restrict__ w1t)
{
    int t = blockIdx.x * blockDim.x + threadIdx.x;   // t = o*64 + i
    if (t < 64 * 256) {
        int i = t & 63;
        int o = t >> 6;
        w1t[t] = w1[i * 256 + o];
    }
}

// One wave per flagged node, 3 layers fused. Neighbor indices/weights are
// cooperatively prefetched (one coalesced load per 64-chunk) into LDS, so the
// gather loop has NO dependent index loads: 6 independent row gathers per
// unrolled iteration can be issued back-to-back.
__global__ __launch_bounds__(64) void apply_updates(
    const float* __restrict__ rp0, const float* __restrict__ rp1,
    const float* __restrict__ rp2, const float* __restrict__ rp3,
    const float* __restrict__ times, const float* __restrict__ now_time, int E,
    const int* __restrict__ row_start, const int* __restrict__ adj_other,
    const float* __restrict__ adj_tw, const int* __restrict__ flag,
    float* __restrict__ new1, float* __restrict__ new2, float* __restrict__ new3)
{
    __shared__ int   s_o[64];
    __shared__ float s_w[64];

    int n = blockIdx.x;
    if (!flag[n]) return;          // row never read downstream
    int lid = threadIdx.x;
    float tlast = times[E - 1];
    float dec = expf(-WDECAY * (tlast - now_time[0]));
    float d2 = dec * dec;
    float d3 = d2 * dec;

    long long base = (long long)n * D + lid * 4;
    float4 a1 = *(const float4*)(rp1 + base);
    float4 a2 = *(const float4*)(rp2 + base);
    float4 a3 = *(const float4*)(rp3 + base);
    a1.x *= dec; a1.y *= dec; a1.z *= dec; a1.w *= dec;
    a2.x *= d2;  a2.y *= d2;  a2.z *= d2;  a2.w *= d2;
    a3.x *= d3;  a3.y *= d3;  a3.z *= d3;  a3.w *= d3;

    int s = row_start[n];
    int e = row_start[n + 1];
    int off = lid * 4;

    for (int cs = s; cs < e; cs += 64) {
        int cnt = e - cs;
        if (cnt > 64) cnt = 64;
        // cooperative index prefetch (single wave: no __syncthreads needed,
        // compiler orders the LDS RAW via lgkmcnt)
        if (lid < cnt) {
            s_o[lid] = adj_other[cs + lid];
            s_w[lid] = adj_tw[cs + lid];
        }
        int k = 0;
        for (; k + 1 < cnt; k += 2) {
            int o0 = s_o[k];
            int o1 = s_o[k + 1];
            float u0 = s_w[k];
            float u1 = s_w[k + 1];
            long long b0 = (long long)o0 * D + off;
            long long b1 = (long long)o1 * D + off;
            float4 v00 = *(const float4*)(rp0 + b0);
            float4 v01 = *(const float4*)(rp1 + b0);
            float4 v02 = *(const float4*)(rp2 + b0);
            float4 v10 = *(const float4*)(rp0 + b1);
            float4 v11 = *(const float4*)(rp1 + b1);
            float4 v12 = *(const float4*)(rp2 + b1);
            a1.x += v00.x * u0 + v10.x * u1; a1.y += v00.y * u0 + v10.y * u1;
            a1.z += v00.z * u0 + v10.z * u1; a1.w += v00.w * u0 + v10.w * u1;
            float h0 = u0 * dec, h1 = u1 * dec;
            a2.x += v01.x * h0 + v11.x * h1; a2.y += v01.y * h0 + v11.y * h1;
            a2.z += v01.z * h0 + v11.z * h1; a2.w += v01.w * h0 + v11.w * h1;
            float q0 = u0 * d2, q1 = u1 * d2;
            a3.x += v02.x * q0 + v12.x * q1; a3.y += v02.y * q0 + v12.y * q1;
            a3.z += v02.z * q0 + v12.z * q1; a3.w += v02.w * q0 + v12.w * q1;
        }
        if (k < cnt) {
            int o0 = s_o[k];
            float u0 = s_w[k];
            long long b0 = (long long)o0 * D + off;
            float4 v00 = *(const float4*)(rp0 + b0);
            float4 v01 = *(const float4*)(rp1 + b0);
            float4 v02 = *(const float4*)(rp2 + b0);
            a1.x += v00.x * u0; a1.y += v00.y * u0; a1.z += v00.z * u0; a1.w += v00.w * u0;
            float h0 = u0 * dec;
            a2.x += v01.x * h0; a2.y += v01.y * h0; a2.z += v01.z * h0; a2.w += v01.w * h0;
            float q0 = u0 * d2;
            a3.x += v02.x * q0; a3.y += v02.y * q0; a3.z += v02.z * q0; a3.w += v02.w * q0;
        }
    }

    *(float4*)(new1 + base) = a1;
    *(float4*)(new2 + base) = a2;
    *(float4*)(new3 + base) = a3;
}

// ---------------- pair feature ----------------

// One wave per pair: gather 8 rows, 8x8 Gram over D=256, log1p.
// Writes feat TRANSPOSED: featT[64][B] so the MLP reads are coalesced.
__global__ __launch_bounds__(64) void gather_gram(
    const float* __restrict__ rp0, const float* __restrict__ new1,
    const float* __restrict__ new2, const float* __restrict__ new3,
    const int* __restrict__ q_src, const int* __restrict__ q_dst,
    float* __restrict__ featT, int B)
{
    __shared__ float proj[8][260];   // stride 260 -> conflict-free b128
    int b = blockIdx.x;
    int lid = threadIdx.x;
    long long qs = q_src[b];
    long long qd = q_dst[b];

    const float* tabs[4] = {rp0, new1, new2, new3};
    #pragma unroll
    for (int r = 0; r < 4; ++r) {
        const float* tp = tabs[r];
        float4 v = *(const float4*)(tp + qs * D + lid * 4);
        *(float4*)&proj[r][lid * 4] = v;
        float4 w = *(const float4*)(tp + qd * D + lid * 4);
        *(float4*)&proj[r + 4][lid * 4] = w;
    }
    __syncthreads();

    int p = lid >> 3;
    int q = lid & 7;
    float acc = 0.f;
    #pragma unroll 8
    for (int k = 0; k < 64; ++k) {
        float4 a = *(const float4*)&proj[p][4 * k];
        float4 c = *(const float4*)&proj[q][4 * k];
        acc += a.x * c.x + a.y * c.y + a.z * c.z + a.w * c.w;
    }
    featT[(long long)lid * B + b] = log1pf(fmaxf(acc, 0.f));
}

// ---------------- MLP: weight-stationary in LDS, pair-per-thread in VGPRs ----

// Block = 256 threads (4 waves), 1 block/CU (129 KB LDS).
// Weights staged once per block into LDS; all weight reads are wave-uniform
// broadcasts (conflict-free). f[64] and acc[64] live in VGPRs (static
// indexing only; __launch_bounds__(256,1) allows up to 512 VGPRs).
__global__ __launch_bounds__(256, 1) void mlp_kernel(
    const float* __restrict__ featT,   // [64][B] transposed features
    const float* __restrict__ w1t,     // [256][64] transposed
    const float* __restrict__ b1,
    const float* __restrict__ w2,      // [256][64]
    const float* __restrict__ b2,
    float* __restrict__ out, int B)
{
    __shared__ float w1s[256 * 64];    // 64 KB
    __shared__ float w2s[256 * 64];    // 64 KB
    __shared__ float b1s[256];         // 1 KB
    int t = threadIdx.x;

    {
        const float4* w1g = (const float4*)w1t;
        const float4* w2g = (const float4*)w2;
        float4* w1d = (float4*)w1s;
        float4* w2d = (float4*)w2s;
        #pragma unroll
        for (int k = 0; k < 16; ++k) {
            int idx = t + 256 * k;
            w1d[idx] = w1g[idx];
            w2d[idx] = w2g[idx];
        }
        b1s[t] = b1[t];
    }

    int pi = blockIdx.x * 256 + t;
    bool valid = (pi < B);

    // coalesced feature loads: lane t reads featT[i*B + p0 + t]
    float f[64];
    #pragma unroll
    for (int i = 0; i < 64; ++i)
        f[i] = valid ? featT[(long long)i * B + pi] : 0.f;

    __syncthreads();

    float4 acc[16];
    #pragma unroll
    for (int k = 0; k < 16; ++k) acc[k] = make_float4(0.f, 0.f, 0.f, 0.f);

    #pragma unroll 2
    for (int o = 0; o < 256; ++o) {
        const float4* w1r = (const float4*)&w1s[o * 64];
        float4 s = make_float4(0.f, 0.f, 0.f, 0.f);
        #pragma unroll
        for (int i = 0; i < 16; ++i) {
            float4 wv = w1r[i];
            s.x += f[4 * i + 0] * wv.x;
            s.y += f[4 * i + 1] * wv.y;
            s.z += f[4 * i + 2] * wv.z;
            s.w += f[4 * i + 3] * wv.w;
        }
        float h = b1s[o] + (s.x + s.y) + (s.z + s.w);
        h = fmaxf(h, 0.f);
        const float4* w2r = (const float4*)&w2s[o * 64];
        #pragma unroll
        for (int k = 0; k < 16; ++k) {
            float4 wv = w2r[k];
            acc[k].x += h * wv.x;
            acc[k].y += h * wv.y;
            acc[k].z += h * wv.z;
            acc[k].w += h * wv.w;
        }
    }

    if (valid) {
        float* op = out + (long long)pi * 64;
        #pragma unroll
        for (int k = 0; k < 16; ++k) {
            float4 bv = *(const float4*)(b2 + 4 * k);
            float4 v = make_float4(acc[k].x + bv.x, acc[k].y + bv.y,
                                   acc[k].z + bv.z, acc[k].w + bv.w);
            *(float4*)(op + 4 * k) = v;
        }
    }
}

// ---------------- fallback (atomic) path ----------------

__global__ __launch_bounds__(256) void init_tables(
    const float* __restrict__ rp1, const float* __restrict__ rp2,
    const float* __restrict__ rp3, const float* __restrict__ times,
    const float* __restrict__ now_time, int E,
    float* __restrict__ new1, float* __restrict__ new2, float* __restrict__ new3,
    long long n4)
{
    float tlast = times[E - 1];
    float dec = expf(-WDECAY * (tlast - now_time[0]));
    float d2 = dec * dec;
    float d3 = d2 * dec;
    const float4* r1 = (const float4*)rp1;
    const float4* r2 = (const float4*)rp2;
    const float4* r3 = (const float4*)rp3;
    float4* n1 = (float4*)new1;
    float4* n2 = (float4*)new2;
    float4* n3 = (float4*)new3;
    long long i = (long long)blockIdx.x * blockDim.x + threadIdx.x;
    long long stride = (long long)gridDim.x * blockDim.x;
    for (; i < n4; i += stride) {
        float4 a = r1[i]; a.x *= dec; a.y *= dec; a.z *= dec; a.w *= dec; n1[i] = a;
        float4 b = r2[i]; b.x *= d2; b.y *= d2; b.z *= d2; b.w *= d2; n2[i] = b;
        float4 c = r3[i]; c.x *= d3; c.y *= d3; c.z *= d3; c.w *= d3; n3[i] = c;
    }
}

__global__ __launch_bounds__(256) void scatter_edges(
    const float* __restrict__ rp0, const float* __restrict__ rp1,
    const float* __restrict__ rp2, const float* __restrict__ times,
    const float* __restrict__ now_time,
    const int* __restrict__ src_ids, const int* __restrict__ dst_ids, int E,
    float* __restrict__ new1, float* __restrict__ new2, float* __restrict__ new3)
{
    int e = blockIdx.x;
    int d = threadIdx.x;
    float tlast = times[E - 1];
    float dec = expf(-WDECAY * (tlast - now_time[0]));
    float d2 = dec * dec;
    float tw = expf(-WDECAY * (tlast - times[e]));
    long long s = src_ids[e];
    long long t = dst_ids[e];
    long long so = s * D + d;
    long long to = t * D + d;
    float a0s = rp0[so], a0t = rp0[to];
    atomicAdd(&new1[so], a0t * tw);
    atomicAdd(&new1[to], a0s * tw);
    float a1s = rp1[so] * dec, a1t = rp1[to] * dec;
    atomicAdd(&new2[so], a1t * tw);
    atomicAdd(&new2[to], a1s * tw);
    float a2s = rp2[so] * d2, a2t = rp2[to] * d2;
    atomicAdd(&new3[so], a2t * tw);
    atomicAdd(&new3[to], a2s * tw);
}

__global__ __launch_bounds__(64) void pair_feature_mlp(
    const float* __restrict__ rp0, const float* __restrict__ new1,
    const float* __restrict__ new2, const float* __restrict__ new3,
    const int* __restrict__ q_src, const int* __restrict__ q_dst,
    const float* __restrict__ w1, const float* __restrict__ b1,
    const float* __restrict__ w2, const float* __restrict__ b2,
    float* __restrict__ out, int B)
{
    __shared__ float proj[8][260];
    __shared__ float feat_s[64];
    __shared__ float h_s[256];

    int b = blockIdx.x;
    int lid = threadIdx.x;
    long long qs = q_src[b];
    long long qd = q_dst[b];

    const float* tabs[4] = {rp0, new1, new2, new3};
    #pragma unroll
    for (int r = 0; r < 4; ++r) {
        const float* tp = tabs[r];
        float4 v = *(const float4*)(tp + qs * D + lid * 4);
        *(float4*)&proj[r][lid * 4] = v;
        float4 w = *(const float4*)(tp + qd * D + lid * 4);
        *(float4*)&proj[r + 4][lid * 4] = w;
    }
    __syncthreads();

    int p = lid >> 3;
    int q = lid & 7;
    float acc = 0.f;
    #pragma unroll 8
    for (int k = 0; k < 64; ++k) {
        float4 a = *(const float4*)&proj[p][4 * k];
        float4 c = *(const float4*)&proj[q][4 * k];
        acc += a.x * c.x + a.y * c.y + a.z * c.z + a.w * c.w;
    }
    feat_s[lid] = log1pf(fmaxf(acc, 0.f));
    __syncthreads();

    float4 hv = *(const float4*)(b1 + 4 * lid);
    #pragma unroll 4
    for (int i = 0; i < 64; ++i) {
        float fv = feat_s[i];
        float4 w = *(const float4*)(w1 + i * 256 + 4 * lid);
        hv.x += fv * w.x; hv.y += fv * w.y; hv.z += fv * w.z; hv.w += fv * w.w;
    }
    *(float4*)&h_s[4 * lid] = make_float4(fmaxf(hv.x, 0.f), fmaxf(hv.y, 0.f),
                                          fmaxf(hv.z, 0.f), fmaxf(hv.w, 0.f));
    __syncthreads();

    float o0 = 0.f, o1 = 0.f, o2 = 0.f, o3 = 0.f;
    #pragma unroll 4
    for (int j = 0; j < 256; j += 4) {
        o0 += h_s[j + 0] * w2[(j + 0) * 64 + lid];
        o1 += h_s[j + 1] * w2[(j + 1) * 64 + lid];
        o2 += h_s[j + 2] * w2[(j + 2) * 64 + lid];
        o3 += h_s[j + 3] * w2[(j + 3) * 64 + lid];
    }
    out[(long long)b * 64 + lid] = b2[lid] + (o0 + o1) + (o2 + o3);
}

extern "C" void kernel_launch(void* const* d_in, const int* in_sizes, int n_in,
                              void* d_out, int out_size, void* d_ws, size_t ws_size,
                              hipStream_t stream)
{
    const float* rp0      = (const float*)d_in[0];
    const float* rp1      = (const float*)d_in[1];
    const float* rp2      = (const float*)d_in[2];
    const float* rp3      = (const float*)d_in[3];
    const float* times    = (const float*)d_in[4];
    const float* now_time = (const float*)d_in[5];
    const float* w1       = (const float*)d_in[6];
    const float* b1       = (const float*)d_in[7];
    const float* w2       = (const float*)d_in[8];
    const float* b2       = (const float*)d_in[9];
    const int*   src_ids  = (const int*)d_in[10];
    const int*   dst_ids  = (const int*)d_in[11];
    const int*   q_src    = (const int*)d_in[12];
    const int*   q_dst    = (const int*)d_in[13];
    float* out = (float*)d_out;

    long long ND = in_sizes[0];      // N * D
    int N = (int)(ND / D);
    int E = in_sizes[4];
    int B = in_sizes[12];
    int NB = (N + CHUNK - 1) / CHUNK;

    float* new1 = (float*)d_ws;
    float* new2 = new1 + ND;
    float* new3 = new2 + ND;

    size_t base_bytes = (size_t)3 * ND * sizeof(float);
    size_t extra_bytes = (size_t)(2 * N + (N + 1) + 2 * E + NB) * sizeof(int)
                       + (size_t)(2 * E) * sizeof(float)
                       + (size_t)B * 64 * sizeof(float)
                       + (size_t)64 * 256 * sizeof(float);

    if (ws_size >= base_bytes + extra_bytes && NB <= 65536) {
        int* cnt       = (int*)(new3 + ND);           // N (becomes cursor)
        int* flag      = cnt + N;                     // N
        int* row_start = flag + N;                    // N+1
        int* adj_other = row_start + N + 1;           // 2E
        float* adj_tw  = (float*)(adj_other + 2 * E); // 2E
        int* bsum      = (int*)(adj_tw + 2 * E);      // NB
        float* featT   = (float*)(bsum + NB);         // 64*B (transposed)
        float* w1t     = featT + (size_t)B * 64;      // 256*64

        hipMemsetAsync(cnt, 0, (size_t)2 * N * sizeof(int), stream);  // cnt + flag
        int twoE = 2 * E;
        hist_kernel<<<(twoE + 255) / 256, 256, 0, stream>>>(src_ids, dst_ids, E, cnt);
        set_flags<<<(B + 255) / 256, 256, 0, stream>>>(q_src, q_dst, B, flag);
        transpose_w1<<<64, 256, 0, stream>>>(w1, w1t);
        scan_partial<<<NB, 256, 0, stream>>>(cnt, N, bsum);
        scan_blocksums<<<1, 256, 0, stream>>>(bsum, NB, row_start, N);
        scan_apply<<<NB, 256, 0, stream>>>(cnt, bsum, row_start, N);
        fill_kernel<<<(twoE + 255) / 256, 256, 0, stream>>>(src_ids, dst_ids, times, E,
                                                            cnt, adj_other, adj_tw);
        apply_updates<<<N, 64, 0, stream>>>(rp0, rp1, rp2, rp3, times, now_time, E,
                                            row_start, adj_other, adj_tw, flag,
                                            new1, new2, new3);
        gather_gram<<<B, 64, 0, stream>>>(rp0, new1, new2, new3, q_src, q_dst, featT, B);
        mlp_kernel<<<(B + 255) / 256, 256, 0, stream>>>(featT, w1t, b1, w2, b2, out, B);
    } else {
        long long n4 = ND / 4;
        init_tables<<<2048, 256, 0, stream>>>(rp1, rp2, rp3, times, now_time, E,
                                              new1, new2, new3, n4);
        scatter_edges<<<E, 256, 0, stream>>>(rp0, rp1, rp2, times, now_time,
                                             src_ids, dst_ids, E, new1, new2, new3);
        pair_feature_mlp<<<B, 64, 0, stream>>>(rp0, new1, new2, new3, q_src, q_dst,
                                               w1, b1, w2, b2, out, B);
    }
}

// Round 4
// 682.223 us; speedup vs baseline: 1.0308x; 1.0308x over previous
//
#include <hip/hip_runtime.h>
#include <math.h>

#define D 256
#define WDECAY 1e-6f
#define CHUNK 1024   // elements per scan block (256 threads x 4)
#define MLP_P 64     // pairs per MLP block

// ---------------- CSR build ----------------

__global__ __launch_bounds__(256) void hist_kernel(
    const int* __restrict__ src, const int* __restrict__ dst, int E,
    int* __restrict__ cnt)
{
    int i = blockIdx.x * blockDim.x + threadIdx.x;
    if (i < 2 * E) {
        int n = (i < E) ? src[i] : dst[i - E];
        atomicAdd(&cnt[n], 1);
    }
}

__global__ __launch_bounds__(256) void scan_partial(
    const int* __restrict__ cnt, int N, int* __restrict__ bsum)
{
    __shared__ int sdata[256];
    int b = blockIdx.x, t = threadIdx.x;
    int base = b * CHUNK + 4 * t;
    int s = 0;
    if (base + 3 < N) {
        int4 v = *(const int4*)(cnt + base);
        s = v.x + v.y + v.z + v.w;
    } else {
        for (int k = 0; k < 4; ++k)
            if (base + k < N) s += cnt[base + k];
    }
    sdata[t] = s;
    __syncthreads();
    for (int off = 128; off > 0; off >>= 1) {
        if (t < off) sdata[t] += sdata[t + off];
        __syncthreads();
    }
    if (t == 0) bsum[b] = sdata[0];
}

__global__ __launch_bounds__(256) void scan_blocksums(
    int* __restrict__ bsum, int NB, int* __restrict__ row_start, int N)
{
    __shared__ int part[256];
    int t = threadIdx.x;
    int per = (NB + 255) / 256;
    int lo = t * per, hi = lo + per;
    if (hi > NB) hi = NB;
    int s = 0;
    for (int i = lo; i < hi; ++i) s += bsum[i];
    part[t] = s;
    __syncthreads();
    for (int off = 1; off < 256; off <<= 1) {
        int v = (t >= off) ? part[t - off] : 0;
        __syncthreads();
        part[t] += v;
        __syncthreads();
    }
    int base = (t == 0) ? 0 : part[t - 1];
    for (int i = lo; i < hi; ++i) {
        int c = bsum[i];
        bsum[i] = base;
        base += c;
    }
    if (t == 255) row_start[N] = part[255];
}

__global__ __launch_bounds__(256) void scan_apply(
    int* __restrict__ cnt, const int* __restrict__ bsum,
    int* __restrict__ row_start, int N)
{
    __shared__ int part[256];
    int b = blockIdx.x, t = threadIdx.x;
    int base = b * CHUNK + 4 * t;
    int4 v = make_int4(0, 0, 0, 0);
    if (base + 3 < N) {
        v = *(const int4*)(cnt + base);
    } else {
        if (base + 0 < N) v.x = cnt[base + 0];
        if (base + 1 < N) v.y = cnt[base + 1];
        if (base + 2 < N) v.z = cnt[base + 2];
    }
    part[t] = v.x + v.y + v.z + v.w;
    __syncthreads();
    for (int off = 1; off < 256; off <<= 1) {
        int pv = (t >= off) ? part[t - off] : 0;
        __syncthreads();
        part[t] += pv;
        __syncthreads();
    }
    int p = bsum[b] + ((t == 0) ? 0 : part[t - 1]);
    int p0 = p, p1 = p0 + v.x, p2 = p1 + v.y, p3 = p2 + v.z;
    if (base + 0 < N) { row_start[base + 0] = p0; cnt[base + 0] = p0; }
    if (base + 1 < N) { row_start[base + 1] = p1; cnt[base + 1] = p1; }
    if (base + 2 < N) { row_start[base + 2] = p2; cnt[base + 2] = p2; }
    if (base + 3 < N) { row_start[base + 3] = p3; cnt[base + 3] = p3; }
}

__global__ __launch_bounds__(256) void fill_kernel(
    const int* __restrict__ src, const int* __restrict__ dst,
    const float* __restrict__ times, int E,
    int* __restrict__ cursor, int* __restrict__ adj_other,
    float* __restrict__ adj_tw)
{
    int i = blockIdx.x * blockDim.x + threadIdx.x;
    if (i >= 2 * E) return;
    int e = (i < E) ? i : i - E;
    int node  = (i < E) ? src[e] : dst[e];
    int other = (i < E) ? dst[e] : src[e];
    float tlast = times[E - 1];
    float w = expf(-WDECAY * (tlast - times[e]));
    int pos = atomicAdd(&cursor[node], 1);
    adj_other[pos] = other;
    adj_tw[pos] = w;
}

// Mark nodes that appear in any query pair.
__global__ __launch_bounds__(256) void set_flags(
    const int* __restrict__ qs, const int* __restrict__ qd, int B,
    int* __restrict__ flag)
{
    int i = blockIdx.x * blockDim.x + threadIdx.x;
    if (i < B) {
        flag[qs[i]] = 1;
        flag[qd[i]] = 1;
    }
}

// One wave per (node, layer), ONLY for nodes read by the query phase.
// NOTE: deliberately NOT fused across layers — R1/R2/R3 A/B showed the
// TLP of 3x more waves beats any attempted ILP (compiler caps in-flight
// gathers regardless of unrolling; VGPR=8 version hit 3.87 TB/s).
__global__ __launch_bounds__(64) void apply_updates(
    const float* __restrict__ rp0, const float* __restrict__ rp1,
    const float* __restrict__ rp2, const float* __restrict__ rp3,
    const float* __restrict__ times, const float* __restrict__ now_time, int E,
    const int* __restrict__ row_start, const int* __restrict__ adj_other,
    const float* __restrict__ adj_tw, const int* __restrict__ flag,
    float* __restrict__ new1, float* __restrict__ new2, float* __restrict__ new3)
{
    int n = blockIdx.x;
    if (!flag[n]) return;          // row never read downstream
    int l = blockIdx.y;
    int lid = threadIdx.x;
    float tlast = times[E - 1];
    float dec = expf(-WDECAY * (tlast - now_time[0]));

    const float* own; const float* gat; float* outp; float os, gs;
    if (l == 0)      { own = rp1; gat = rp0; outp = new1; os = dec;             gs = 1.f;       }
    else if (l == 1) { own = rp2; gat = rp1; outp = new2; os = dec * dec;       gs = dec;       }
    else             { own = rp3; gat = rp2; outp = new3; os = dec * dec * dec; gs = dec * dec; }

    long long base = (long long)n * D + lid * 4;
    float4 acc = *(const float4*)(own + base);
    acc.x *= os; acc.y *= os; acc.z *= os; acc.w *= os;

    int s = row_start[n];
    int e = row_start[n + 1];
    for (int j = s; j < e; ++j) {
        int o = adj_other[j];
        float w = adj_tw[j] * gs;
        float4 v = *(const float4*)(gat + (long long)o * D + lid * 4);
        acc.x += v.x * w; acc.y += v.y * w; acc.z += v.z * w; acc.w += v.w * w;
    }
    *(float4*)(outp + base) = acc;
}

// ---------------- pair feature ----------------

// One wave per pair: gather 8 rows, 8x8 Gram over D=256, log1p.
// Writes feat TRANSPOSED: featT[64][B] so the MLP reads are coalesced.
__global__ __launch_bounds__(64) void gather_gram(
    const float* __restrict__ rp0, const float* __restrict__ new1,
    const float* __restrict__ new2, const float* __restrict__ new3,
    const int* __restrict__ q_src, const int* __restrict__ q_dst,
    float* __restrict__ featT, int B)
{
    __shared__ float proj[8][260];   // stride 260 -> conflict-free b128
    int b = blockIdx.x;
    int lid = threadIdx.x;
    long long qs = q_src[b];
    long long qd = q_dst[b];

    const float* tabs[4] = {rp0, new1, new2, new3};
    #pragma unroll
    for (int r = 0; r < 4; ++r) {
        const float* tp = tabs[r];
        float4 v = *(const float4*)(tp + qs * D + lid * 4);
        *(float4*)&proj[r][lid * 4] = v;
        float4 w = *(const float4*)(tp + qd * D + lid * 4);
        *(float4*)&proj[r + 4][lid * 4] = w;
    }
    __syncthreads();

    int p = lid >> 3;
    int q = lid & 7;
    float acc = 0.f;
    #pragma unroll 8
    for (int k = 0; k < 64; ++k) {
        float4 a = *(const float4*)&proj[p][4 * k];
        float4 c = *(const float4*)&proj[q][4 * k];
        acc += a.x * c.x + a.y * c.y + a.z * c.z + a.w * c.w;
    }
    featT[(long long)lid * B + b] = log1pf(fmaxf(acc, 0.f));
}

// ---------------- MLP: register-tiled two-phase GEMM ----------------
// out = relu(F @ W1 + b1) @ W2 + b2 per 64-pair tile.
// Phase 1: 8p x 8o register tiles; F from LDS (per-lane b128), W1 from
// global (L2-hot, coalesced b32 with o-interleaving). Phase 2: 4p x 4c
// tiles; H from LDS broadcast b32, W2 rows coalesced from global.
// All LDS traffic is per-lane vectorized or broadcast — no uniform-b128
// bandwidth waste (the previous version's bottleneck).
__global__ __launch_bounds__(256, 1) void mlp_kernel(
    const float* __restrict__ featT,   // [64][B] transposed features
    const float* __restrict__ w1,      // [64][256] native (k-major)
    const float* __restrict__ b1,      // [256]
    const float* __restrict__ w2,      // [256][64]
    const float* __restrict__ b2,      // [64]
    float* __restrict__ out, int B)
{
    __shared__ float fsT[64][68];      // [k][p], 17 KB, b128-aligned rows
    __shared__ float hT[256][65];      // [o][p], 65 KB, pad 65 -> bank spread
    int t = threadIdx.x;
    int p0 = blockIdx.x * MLP_P;

    // stage feature tile: fsT[k][p] = featT[k][p0+p] (coalesced)
    {
        int p = t & 63;
        int gp = p0 + p;
        bool valid = (gp < B);
        #pragma unroll
        for (int r = 0; r < 16; ++r) {
            int k = (t >> 6) + 4 * r;
            fsT[k][p] = valid ? featT[(long long)k * B + gp] : 0.f;
        }
    }
    __syncthreads();

    // ---- phase 1: H = relu(F @ W1 + b1) ----
    // thread (tp,to): pairs p = tp*8..+7, outputs o = to + 32*j (j=0..7)
    {
        int tp = t >> 5;          // 0..7
        int to = t & 31;          // 0..31
        float acc[8][8];
        #pragma unroll
        for (int i = 0; i < 8; ++i)
            #pragma unroll
            for (int j = 0; j < 8; ++j) acc[i][j] = 0.f;

        #pragma unroll 4
        for (int k = 0; k < 64; ++k) {
            float4 fA = *(const float4*)&fsT[k][tp * 8];
            float4 fB = *(const float4*)&fsT[k][tp * 8 + 4];
            const float* wr = w1 + k * 256 + to;
            float w[8];
            #pragma unroll
            for (int j = 0; j < 8; ++j) w[j] = wr[32 * j];
            float f0 = fA.x, f1 = fA.y, f2 = fA.z, f3 = fA.w;
            float f4 = fB.x, f5 = fB.y, f6 = fB.z, f7 = fB.w;
            #pragma unroll
            for (int j = 0; j < 8; ++j) {
                acc[0][j] += f0 * w[j]; acc[1][j] += f1 * w[j];
                acc[2][j] += f2 * w[j]; acc[3][j] += f3 * w[j];
                acc[4][j] += f4 * w[j]; acc[5][j] += f5 * w[j];
                acc[6][j] += f6 * w[j]; acc[7][j] += f7 * w[j];
            }
        }
        #pragma unroll
        for (int j = 0; j < 8; ++j) {
            int o = to + 32 * j;
            float bb = b1[o];
            #pragma unroll
            for (int i = 0; i < 8; ++i)
                hT[o][tp * 8 + i] = fmaxf(acc[i][j] + bb, 0.f);
        }
    }
    __syncthreads();

    // ---- phase 2: out = H @ W2 + b2 ----
    // thread (tp2,tc): pairs p = tp2*4..+3, cols c = tc*4..+3
    {
        int tp2 = t >> 4;         // 0..15
        int tc  = t & 15;         // 0..15
        float a0x = 0.f, a0y = 0.f, a0z = 0.f, a0w = 0.f;
        float a1x = 0.f, a1y = 0.f, a1z = 0.f, a1w = 0.f;
        float a2x = 0.f, a2y = 0.f, a2z = 0.f, a2w = 0.f;
        float a3x = 0.f, a3y = 0.f, a3z = 0.f, a3w = 0.f;

        #pragma unroll 4
        for (int k = 0; k < 256; ++k) {
            float h0 = hT[k][tp2 * 4 + 0];
            float h1 = hT[k][tp2 * 4 + 1];
            float h2 = hT[k][tp2 * 4 + 2];
            float h3 = hT[k][tp2 * 4 + 3];
            float4 wv = *(const float4*)&w2[k * 64 + tc * 4];
            a0x += h0 * wv.x; a0y += h0 * wv.y; a0z += h0 * wv.z; a0w += h0 * wv.w;
            a1x += h1 * wv.x; a1y += h1 * wv.y; a1z += h1 * wv.z; a1w += h1 * wv.w;
            a2x += h2 * wv.x; a2y += h2 * wv.y; a2z += h2 * wv.z; a2w += h2 * wv.w;
            a3x += h3 * wv.x; a3y += h3 * wv.y; a3z += h3 * wv.z; a3w += h3 * wv.w;
        }
        float4 bv = *(const float4*)&b2[tc * 4];
        int gp = p0 + tp2 * 4;
        float* op = out + (long long)gp * 64 + tc * 4;
        if (gp + 0 < B) *(float4*)(op + 0 * 64) =
            make_float4(a0x + bv.x, a0y + bv.y, a0z + bv.z, a0w + bv.w);
        if (gp + 1 < B) *(float4*)(op + 1 * 64) =
            make_float4(a1x + bv.x, a1y + bv.y, a1z + bv.z, a1w + bv.w);
        if (gp + 2 < B) *(float4*)(op + 2 * 64) =
            make_float4(a2x + bv.x, a2y + bv.y, a2z + bv.z, a2w + bv.w);
        if (gp + 3 < B) *(float4*)(op + 3 * 64) =
            make_float4(a3x + bv.x, a3y + bv.y, a3z + bv.z, a3w + bv.w);
    }
}

// ---------------- fallback (atomic) path ----------------

__global__ __launch_bounds__(256) void init_tables(
    const float* __restrict__ rp1, const float* __restrict__ rp2,
    const float* __restrict__ rp3, const float* __restrict__ times,
    const float* __restrict__ now_time, int E,
    float* __restrict__ new1, float* __restrict__ new2, float* __restrict__ new3,
    long long n4)
{
    float tlast = times[E - 1];
    float dec = expf(-WDECAY * (tlast - now_time[0]));
    float d2 = dec * dec;
    float d3 = d2 * dec;
    const float4* r1 = (const float4*)rp1;
    const float4* r2 = (const float4*)rp2;
    const float4* r3 = (const float4*)rp3;
    float4* n1 = (float4*)new1;
    float4* n2 = (float4*)new2;
    float4* n3 = (float4*)new3;
    long long i = (long long)blockIdx.x * blockDim.x + threadIdx.x;
    long long stride = (long long)gridDim.x * blockDim.x;
    for (; i < n4; i += stride) {
        float4 a = r1[i]; a.x *= dec; a.y *= dec; a.z *= dec; a.w *= dec; n1[i] = a;
        float4 b = r2[i]; b.x *= d2; b.y *= d2; b.z *= d2; b.w *= d2; n2[i] = b;
        float4 c = r3[i]; c.x *= d3; c.y *= d3; c.z *= d3; c.w *= d3; n3[i] = c;
    }
}

__global__ __launch_bounds__(256) void scatter_edges(
    const float* __restrict__ rp0, const float* __restrict__ rp1,
    const float* __restrict__ rp2, const float* __restrict__ times,
    const float* __restrict__ now_time,
    const int* __restrict__ src_ids, const int* __restrict__ dst_ids, int E,
    float* __restrict__ new1, float* __restrict__ new2, float* __restrict__ new3)
{
    int e = blockIdx.x;
    int d = threadIdx.x;
    float tlast = times[E - 1];
    float dec = expf(-WDECAY * (tlast - now_time[0]));
    float d2 = dec * dec;
    float tw = expf(-WDECAY * (tlast - times[e]));
    long long s = src_ids[e];
    long long t = dst_ids[e];
    long long so = s * D + d;
    long long to = t * D + d;
    float a0s = rp0[so], a0t = rp0[to];
    atomicAdd(&new1[so], a0t * tw);
    atomicAdd(&new1[to], a0s * tw);
    float a1s = rp1[so] * dec, a1t = rp1[to] * dec;
    atomicAdd(&new2[so], a1t * tw);
    atomicAdd(&new2[to], a1s * tw);
    float a2s = rp2[so] * d2, a2t = rp2[to] * d2;
    atomicAdd(&new3[so], a2t * tw);
    atomicAdd(&new3[to], a2s * tw);
}

__global__ __launch_bounds__(64) void pair_feature_mlp(
    const float* __restrict__ rp0, const float* __restrict__ new1,
    const float* __restrict__ new2, const float* __restrict__ new3,
    const int* __restrict__ q_src, const int* __restrict__ q_dst,
    const float* __restrict__ w1, const float* __restrict__ b1,
    const float* __restrict__ w2, const float* __restrict__ b2,
    float* __restrict__ out, int B)
{
    __shared__ float proj[8][260];
    __shared__ float feat_s[64];
    __shared__ float h_s[256];

    int b = blockIdx.x;
    int lid = threadIdx.x;
    long long qs = q_src[b];
    long long qd = q_dst[b];

    const float* tabs[4] = {rp0, new1, new2, new3};
    #pragma unroll
    for (int r = 0; r < 4; ++r) {
        const float* tp = tabs[r];
        float4 v = *(const float4*)(tp + qs * D + lid * 4);
        *(float4*)&proj[r][lid * 4] = v;
        float4 w = *(const float4*)(tp + qd * D + lid * 4);
        *(float4*)&proj[r + 4][lid * 4] = w;
    }
    __syncthreads();

    int p = lid >> 3;
    int q = lid & 7;
    float acc = 0.f;
    #pragma unroll 8
    for (int k = 0; k < 64; ++k) {
        float4 a = *(const float4*)&proj[p][4 * k];
        float4 c = *(const float4*)&proj[q][4 * k];
        acc += a.x * c.x + a.y * c.y + a.z * c.z + a.w * c.w;
    }
    feat_s[lid] = log1pf(fmaxf(acc, 0.f));
    __syncthreads();

    float4 hv = *(const float4*)(b1 + 4 * lid);
    #pragma unroll 4
    for (int i = 0; i < 64; ++i) {
        float fv = feat_s[i];
        float4 w = *(const float4*)(w1 + i * 256 + 4 * lid);
        hv.x += fv * w.x; hv.y += fv * w.y; hv.z += fv * w.z; hv.w += fv * w.w;
    }
    *(float4*)&h_s[4 * lid] = make_float4(fmaxf(hv.x, 0.f), fmaxf(hv.y, 0.f),
                                          fmaxf(hv.z, 0.f), fmaxf(hv.w, 0.f));
    __syncthreads();

    float o0 = 0.f, o1 = 0.f, o2 = 0.f, o3 = 0.f;
    #pragma unroll 4
    for (int j = 0; j < 256; j += 4) {
        o0 += h_s[j + 0] * w2[(j + 0) * 64 + lid];
        o1 += h_s[j + 1] * w2[(j + 1) * 64 + lid];
        o2 += h_s[j + 2] * w2[(j + 2) * 64 + lid];
        o3 += h_s[j + 3] * w2[(j + 3) * 64 + lid];
    }
    out[(long long)b * 64 + lid] = b2[lid] + (o0 + o1) + (o2 + o3);
}

extern "C" void kernel_launch(void* const* d_in, const int* in_sizes, int n_in,
                              void* d_out, int out_size, void* d_ws, size_t ws_size,
                              hipStream_t stream)
{
    const float* rp0      = (const float*)d_in[0];
    const float* rp1      = (const float*)d_in[1];
    const float* rp2      = (const float*)d_in[2];
    const float* rp3      = (const float*)d_in[3];
    const float* times    = (const float*)d_in[4];
    const float* now_time = (const float*)d_in[5];
    const float* w1       = (const float*)d_in[6];
    const float* b1       = (const float*)d_in[7];
    const float* w2       = (const float*)d_in[8];
    const float* b2       = (const float*)d_in[9];
    const int*   src_ids  = (const int*)d_in[10];
    const int*   dst_ids  = (const int*)d_in[11];
    const int*   q_src    = (const int*)d_in[12];
    const int*   q_dst    = (const int*)d_in[13];
    float* out = (float*)d_out;

    long long ND = in_sizes[0];      // N * D
    int N = (int)(ND / D);
    int E = in_sizes[4];
    int B = in_sizes[12];
    int NB = (N + CHUNK - 1) / CHUNK;

    float* new1 = (float*)d_ws;
    float* new2 = new1 + ND;
    float* new3 = new2 + ND;

    size_t base_bytes = (size_t)3 * ND * sizeof(float);
    size_t extra_bytes = (size_t)(2 * N + (N + 1) + 2 * E + NB) * sizeof(int)
                       + (size_t)(2 * E) * sizeof(float)
                       + (size_t)B * 64 * sizeof(float);

    if (ws_size >= base_bytes + extra_bytes && NB <= 65536) {
        int* cnt       = (int*)(new3 + ND);           // N (becomes cursor)
        int* flag      = cnt + N;                     // N
        int* row_start = flag + N;                    // N+1
        int* adj_other = row_start + N + 1;           // 2E
        float* adj_tw  = (float*)(adj_other + 2 * E); // 2E
        int* bsum      = (int*)(adj_tw + 2 * E);      // NB
        float* featT   = (float*)(bsum + NB);         // 64*B (transposed)

        hipMemsetAsync(cnt, 0, (size_t)2 * N * sizeof(int), stream);  // cnt + flag
        int twoE = 2 * E;
        hist_kernel<<<(twoE + 255) / 256, 256, 0, stream>>>(src_ids, dst_ids, E, cnt);
        set_flags<<<(B + 255) / 256, 256, 0, stream>>>(q_src, q_dst, B, flag);
        scan_partial<<<NB, 256, 0, stream>>>(cnt, N, bsum);
        scan_blocksums<<<1, 256, 0, stream>>>(bsum, NB, row_start, N);
        scan_apply<<<NB, 256, 0, stream>>>(cnt, bsum, row_start, N);
        fill_kernel<<<(twoE + 255) / 256, 256, 0, stream>>>(src_ids, dst_ids, times, E,
                                                            cnt, adj_other, adj_tw);
        dim3 grid(N, 3);
        apply_updates<<<grid, 64, 0, stream>>>(rp0, rp1, rp2, rp3, times, now_time, E,
                                               row_start, adj_other, adj_tw, flag,
                                               new1, new2, new3);
        gather_gram<<<B, 64, 0, stream>>>(rp0, new1, new2, new3, q_src, q_dst, featT, B);
        mlp_kernel<<<(B + MLP_P - 1) / MLP_P, 256, 0, stream>>>(featT, w1, b1, w2, b2,
                                                                out, B);
    } else {
        long long n4 = ND / 4;
        init_tables<<<2048, 256, 0, stream>>>(rp1, rp2, rp3, times, now_time, E,
                                              new1, new2, new3, n4);
        scatter_edges<<<E, 256, 0, stream>>>(rp0, rp1, rp2, times, now_time,
                                             src_ids, dst_ids, E, new1, new2, new3);
        pair_feature_mlp<<<B, 64, 0, stream>>>(rp0, new1, new2, new3, q_src, q_dst,
                                               w1, b1, w2, b2, out, B);
    }
}

// Round 5
// 671.855 us; speedup vs baseline: 1.0467x; 1.0154x over previous
//
#include <hip/hip_runtime.h>
#include <math.h>

#define D 256
#define WDECAY 1e-6f
#define CHUNK 1024   // elements per scan block (256 threads x 4)
#define MLP_P 64     // pairs per MLP block

// ---------------- CSR build ----------------

__global__ __launch_bounds__(256) void hist_kernel(
    const int* __restrict__ src, const int* __restrict__ dst, int E,
    int* __restrict__ cnt)
{
    int i = blockIdx.x * blockDim.x + threadIdx.x;
    if (i < 2 * E) {
        int n = (i < E) ? src[i] : dst[i - E];
        atomicAdd(&cnt[n], 1);
    }
}

__global__ __launch_bounds__(256) void scan_partial(
    const int* __restrict__ cnt, int N, int* __restrict__ bsum)
{
    __shared__ int sdata[256];
    int b = blockIdx.x, t = threadIdx.x;
    int base = b * CHUNK + 4 * t;
    int s = 0;
    if (base + 3 < N) {
        int4 v = *(const int4*)(cnt + base);
        s = v.x + v.y + v.z + v.w;
    } else {
        for (int k = 0; k < 4; ++k)
            if (base + k < N) s += cnt[base + k];
    }
    sdata[t] = s;
    __syncthreads();
    for (int off = 128; off > 0; off >>= 1) {
        if (t < off) sdata[t] += sdata[t + off];
        __syncthreads();
    }
    if (t == 0) bsum[b] = sdata[0];
}

__global__ __launch_bounds__(256) void scan_blocksums(
    int* __restrict__ bsum, int NB, int* __restrict__ row_start, int N)
{
    __shared__ int part[256];
    int t = threadIdx.x;
    int per = (NB + 255) / 256;
    int lo = t * per, hi = lo + per;
    if (hi > NB) hi = NB;
    int s = 0;
    for (int i = lo; i < hi; ++i) s += bsum[i];
    part[t] = s;
    __syncthreads();
    for (int off = 1; off < 256; off <<= 1) {
        int v = (t >= off) ? part[t - off] : 0;
        __syncthreads();
        part[t] += v;
        __syncthreads();
    }
    int base = (t == 0) ? 0 : part[t - 1];
    for (int i = lo; i < hi; ++i) {
        int c = bsum[i];
        bsum[i] = base;
        base += c;
    }
    if (t == 255) row_start[N] = part[255];
}

__global__ __launch_bounds__(256) void scan_apply(
    int* __restrict__ cnt, const int* __restrict__ bsum,
    int* __restrict__ row_start, int N)
{
    __shared__ int part[256];
    int b = blockIdx.x, t = threadIdx.x;
    int base = b * CHUNK + 4 * t;
    int4 v = make_int4(0, 0, 0, 0);
    if (base + 3 < N) {
        v = *(const int4*)(cnt + base);
    } else {
        if (base + 0 < N) v.x = cnt[base + 0];
        if (base + 1 < N) v.y = cnt[base + 1];
        if (base + 2 < N) v.z = cnt[base + 2];
    }
    part[t] = v.x + v.y + v.z + v.w;
    __syncthreads();
    for (int off = 1; off < 256; off <<= 1) {
        int pv = (t >= off) ? part[t - off] : 0;
        __syncthreads();
        part[t] += pv;
        __syncthreads();
    }
    int p = bsum[b] + ((t == 0) ? 0 : part[t - 1]);
    int p0 = p, p1 = p0 + v.x, p2 = p1 + v.y, p3 = p2 + v.z;
    if (base + 0 < N) { row_start[base + 0] = p0; cnt[base + 0] = p0; }
    if (base + 1 < N) { row_start[base + 1] = p1; cnt[base + 1] = p1; }
    if (base + 2 < N) { row_start[base + 2] = p2; cnt[base + 2] = p2; }
    if (base + 3 < N) { row_start[base + 3] = p3; cnt[base + 3] = p3; }
}

__global__ __launch_bounds__(256) void fill_kernel(
    const int* __restrict__ src, const int* __restrict__ dst,
    const float* __restrict__ times, int E,
    int* __restrict__ cursor, int* __restrict__ adj_other,
    float* __restrict__ adj_tw)
{
    int i = blockIdx.x * blockDim.x + threadIdx.x;
    if (i >= 2 * E) return;
    int e = (i < E) ? i : i - E;
    int node  = (i < E) ? src[e] : dst[e];
    int other = (i < E) ? dst[e] : src[e];
    float tlast = times[E - 1];
    float w = expf(-WDECAY * (tlast - times[e]));
    int pos = atomicAdd(&cursor[node], 1);
    adj_other[pos] = other;
    adj_tw[pos] = w;
}

// Mark nodes that appear in any query pair.
__global__ __launch_bounds__(256) void set_flags(
    const int* __restrict__ qs, const int* __restrict__ qd, int B,
    int* __restrict__ flag)
{
    int i = blockIdx.x * blockDim.x + threadIdx.x;
    if (i < B) {
        flag[qs[i]] = 1;
        flag[qd[i]] = 1;
    }
}

// One wave per (node, layer) — R1/R2/R3 A/B showed this TLP-max config wins
// over layer fusion. NEW: depth-4 rotating register prefetch (static slot
// indices only) so each wave keeps ~4 row-gathers in flight instead of 1.
__global__ __launch_bounds__(64) void apply_updates(
    const float* __restrict__ rp0, const float* __restrict__ rp1,
    const float* __restrict__ rp2, const float* __restrict__ rp3,
    const float* __restrict__ times, const float* __restrict__ now_time, int E,
    const int* __restrict__ row_start, const int* __restrict__ adj_other,
    const float* __restrict__ adj_tw, const int* __restrict__ flag,
    float* __restrict__ new1, float* __restrict__ new2, float* __restrict__ new3)
{
    int n = blockIdx.x;
    if (!flag[n]) return;          // row never read downstream
    int l = blockIdx.y;
    int lid = threadIdx.x;
    float tlast = times[E - 1];
    float dec = expf(-WDECAY * (tlast - now_time[0]));

    const float* own; const float* gat; float* outp; float os, gs;
    if (l == 0)      { own = rp1; gat = rp0; outp = new1; os = dec;             gs = 1.f;       }
    else if (l == 1) { own = rp2; gat = rp1; outp = new2; os = dec * dec;       gs = dec;       }
    else             { own = rp3; gat = rp2; outp = new3; os = dec * dec * dec; gs = dec * dec; }

    long long base = (long long)n * D + lid * 4;
    float4 acc = *(const float4*)(own + base);
    acc.x *= os; acc.y *= os; acc.z *= os; acc.w *= os;

    int s = row_start[n];
    int e = row_start[n + 1];
    int cnt = e - s;
    long long off = lid * 4;

    float4 v0, v1, v2, v3;
    float u0 = 0.f, u1 = 0.f, u2 = 0.f, u3 = 0.f;

    // prologue: fill up to 4 slots (static indices)
    if (cnt > 0) { int o = adj_other[s + 0]; u0 = adj_tw[s + 0];
                   v0 = *(const float4*)(gat + (long long)o * D + off); }
    if (cnt > 1) { int o = adj_other[s + 1]; u1 = adj_tw[s + 1];
                   v1 = *(const float4*)(gat + (long long)o * D + off); }
    if (cnt > 2) { int o = adj_other[s + 2]; u2 = adj_tw[s + 2];
                   v2 = *(const float4*)(gat + (long long)o * D + off); }
    if (cnt > 3) { int o = adj_other[s + 3]; u3 = adj_tw[s + 3];
                   v3 = *(const float4*)(gat + (long long)o * D + off); }

#define STEP(V, U)                                                        \
    {                                                                     \
        float w = (U) * gs;                                               \
        float4 v = (V);                                                   \
        int jn = j + 4 + _slot;                                           \
        if (jn < cnt) {                                                   \
            int o = adj_other[s + jn];                                    \
            (U) = adj_tw[s + jn];                                         \
            (V) = *(const float4*)(gat + (long long)o * D + off);         \
        }                                                                 \
        acc.x += v.x * w; acc.y += v.y * w;                               \
        acc.z += v.z * w; acc.w += v.w * w;                               \
        ++_slot;                                                          \
    }

    int j = 0;
    for (; j + 4 <= cnt; j += 4) {
        int _slot = 0;
        STEP(v0, u0)
        STEP(v1, u1)
        STEP(v2, u2)
        STEP(v3, u3)
    }
    // tail: j % 4 == 0; slots 0..rem-1 hold elements j..j+rem-1
    int rem = cnt - j;
    if (rem > 0) { acc.x += v0.x * u0 * gs; acc.y += v0.y * u0 * gs;
                   acc.z += v0.z * u0 * gs; acc.w += v0.w * u0 * gs; }
    if (rem > 1) { acc.x += v1.x * u1 * gs; acc.y += v1.y * u1 * gs;
                   acc.z += v1.z * u1 * gs; acc.w += v1.w * u1 * gs; }
    if (rem > 2) { acc.x += v2.x * u2 * gs; acc.y += v2.y * u2 * gs;
                   acc.z += v2.z * u2 * gs; acc.w += v2.w * u2 * gs; }
#undef STEP

    *(float4*)(outp + base) = acc;
}

// ---------------- pair feature ----------------

// One wave per pair: gather 8 rows, 8x8 Gram over D=256, log1p.
// Writes feat TRANSPOSED: featT[64][B] so the MLP reads are coalesced.
__global__ __launch_bounds__(64) void gather_gram(
    const float* __restrict__ rp0, const float* __restrict__ new1,
    const float* __restrict__ new2, const float* __restrict__ new3,
    const int* __restrict__ q_src, const int* __restrict__ q_dst,
    float* __restrict__ featT, int B)
{
    __shared__ float proj[8][260];   // stride 260 -> conflict-free b128
    int b = blockIdx.x;
    int lid = threadIdx.x;
    long long qs = q_src[b];
    long long qd = q_dst[b];

    const float* tabs[4] = {rp0, new1, new2, new3};
    #pragma unroll
    for (int r = 0; r < 4; ++r) {
        const float* tp = tabs[r];
        float4 v = *(const float4*)(tp + qs * D + lid * 4);
        *(float4*)&proj[r][lid * 4] = v;
        float4 w = *(const float4*)(tp + qd * D + lid * 4);
        *(float4*)&proj[r + 4][lid * 4] = w;
    }
    __syncthreads();

    int p = lid >> 3;
    int q = lid & 7;
    float acc = 0.f;
    #pragma unroll 8
    for (int k = 0; k < 64; ++k) {
        float4 a = *(const float4*)&proj[p][4 * k];
        float4 c = *(const float4*)&proj[q][4 * k];
        acc += a.x * c.x + a.y * c.y + a.z * c.z + a.w * c.w;
    }
    featT[(long long)lid * B + b] = log1pf(fmaxf(acc, 0.f));
}

// ---------------- MLP: register-tiled two-phase GEMM, weights in LDS ----
// out = relu(F @ W1 + b1) @ W2 + b2 per 64-pair tile.
// v4: W1 is staged in LDS (64 KB) so phase 1's inner loop has ZERO global
// loads — v3's 512 strided global w1 loads/thread at 1 wave/SIMD were
// latency-exposed (no TLP at 1 block/CU). LDS total 149.5 KB <= 160 KB.
__global__ __launch_bounds__(256, 1) void mlp_kernel(
    const float* __restrict__ featT,   // [64][B] transposed features
    const float* __restrict__ w1,      // [64][256] native (k-major)
    const float* __restrict__ b1,      // [256]
    const float* __restrict__ w2,      // [256][64]
    const float* __restrict__ b2,      // [64]
    float* __restrict__ out, int B)
{
    __shared__ float fsT[64][68];      // [k][p], 17 KB
    __shared__ float w1s[64 * 256];    // [k][o], 64 KB
    __shared__ float hT[256][65];      // [o][p], 65 KB
    int t = threadIdx.x;
    int p0 = blockIdx.x * MLP_P;

    // stage W1 (coalesced b128: 4096 float4 / 256 threads = 16 each)
    {
        const float4* wg = (const float4*)w1;
        float4* wd = (float4*)w1s;
        #pragma unroll
        for (int r = 0; r < 16; ++r) wd[t + 256 * r] = wg[t + 256 * r];
    }
    // stage feature tile: fsT[k][p] = featT[k][p0+p] (coalesced)
    {
        int p = t & 63;
        int gp = p0 + p;
        bool valid = (gp < B);
        #pragma unroll
        for (int r = 0; r < 16; ++r) {
            int k = (t >> 6) + 4 * r;
            fsT[k][p] = valid ? featT[(long long)k * B + gp] : 0.f;
        }
    }
    __syncthreads();

    // ---- phase 1: H = relu(F @ W1 + b1) ----
    // thread (tp,to): pairs p = tp*8..+7, outputs o = to + 32*j (j=0..7)
    {
        int tp = t >> 5;          // 0..7
        int to = t & 31;          // 0..31
        float acc[8][8];
        #pragma unroll
        for (int i = 0; i < 8; ++i)
            #pragma unroll
            for (int j = 0; j < 8; ++j) acc[i][j] = 0.f;

        #pragma unroll 4
        for (int k = 0; k < 64; ++k) {
            float4 fA = *(const float4*)&fsT[k][tp * 8];
            float4 fB = *(const float4*)&fsT[k][tp * 8 + 4];
            const float* wr = w1s + k * 256 + to;   // LDS, conflict-free b32
            float w[8];
            #pragma unroll
            for (int j = 0; j < 8; ++j) w[j] = wr[32 * j];
            float f0 = fA.x, f1 = fA.y, f2 = fA.z, f3 = fA.w;
            float f4 = fB.x, f5 = fB.y, f6 = fB.z, f7 = fB.w;
            #pragma unroll
            for (int j = 0; j < 8; ++j) {
                acc[0][j] += f0 * w[j]; acc[1][j] += f1 * w[j];
                acc[2][j] += f2 * w[j]; acc[3][j] += f3 * w[j];
                acc[4][j] += f4 * w[j]; acc[5][j] += f5 * w[j];
                acc[6][j] += f6 * w[j]; acc[7][j] += f7 * w[j];
            }
        }
        #pragma unroll
        for (int j = 0; j < 8; ++j) {
            int o = to + 32 * j;
            float bb = b1[o];
            #pragma unroll
            for (int i = 0; i < 8; ++i)
                hT[o][tp * 8 + i] = fmaxf(acc[i][j] + bb, 0.f);
        }
    }
    __syncthreads();

    // ---- phase 2: out = H @ W2 + b2 ----
    // thread (tp2,tc): pairs p = tp2*4..+3, cols c = tc*4..+3
    {
        int tp2 = t >> 4;         // 0..15
        int tc  = t & 15;         // 0..15
        float a0x = 0.f, a0y = 0.f, a0z = 0.f, a0w = 0.f;
        float a1x = 0.f, a1y = 0.f, a1z = 0.f, a1w = 0.f;
        float a2x = 0.f, a2y = 0.f, a2z = 0.f, a2w = 0.f;
        float a3x = 0.f, a3y = 0.f, a3z = 0.f, a3w = 0.f;

        #pragma unroll 8
        for (int k = 0; k < 256; ++k) {
            float h0 = hT[k][tp2 * 4 + 0];
            float h1 = hT[k][tp2 * 4 + 1];
            float h2 = hT[k][tp2 * 4 + 2];
            float h3 = hT[k][tp2 * 4 + 3];
            float4 wv = *(const float4*)&w2[k * 64 + tc * 4];
            a0x += h0 * wv.x; a0y += h0 * wv.y; a0z += h0 * wv.z; a0w += h0 * wv.w;
            a1x += h1 * wv.x; a1y += h1 * wv.y; a1z += h1 * wv.z; a1w += h1 * wv.w;
            a2x += h2 * wv.x; a2y += h2 * wv.y; a2z += h2 * wv.z; a2w += h2 * wv.w;
            a3x += h3 * wv.x; a3y += h3 * wv.y; a3z += h3 * wv.z; a3w += h3 * wv.w;
        }
        float4 bv = *(const float4*)&b2[tc * 4];
        int gp = p0 + tp2 * 4;
        float* op = out + (long long)gp * 64 + tc * 4;
        if (gp + 0 < B) *(float4*)(op + 0 * 64) =
            make_float4(a0x + bv.x, a0y + bv.y, a0z + bv.z, a0w + bv.w);
        if (gp + 1 < B) *(float4*)(op + 1 * 64) =
            make_float4(a1x + bv.x, a1y + bv.y, a1z + bv.z, a1w + bv.w);
        if (gp + 2 < B) *(float4*)(op + 2 * 64) =
            make_float4(a2x + bv.x, a2y + bv.y, a2z + bv.z, a2w + bv.w);
        if (gp + 3 < B) *(float4*)(op + 3 * 64) =
            make_float4(a3x + bv.x, a3y + bv.y, a3z + bv.z, a3w + bv.w);
    }
}

// ---------------- fallback (atomic) path ----------------

__global__ __launch_bounds__(256) void init_tables(
    const float* __restrict__ rp1, const float* __restrict__ rp2,
    const float* __restrict__ rp3, const float* __restrict__ times,
    const float* __restrict__ now_time, int E,
    float* __restrict__ new1, float* __restrict__ new2, float* __restrict__ new3,
    long long n4)
{
    float tlast = times[E - 1];
    float dec = expf(-WDECAY * (tlast - now_time[0]));
    float d2 = dec * dec;
    float d3 = d2 * dec;
    const float4* r1 = (const float4*)rp1;
    const float4* r2 = (const float4*)rp2;
    const float4* r3 = (const float4*)rp3;
    float4* n1 = (float4*)new1;
    float4* n2 = (float4*)new2;
    float4* n3 = (float4*)new3;
    long long i = (long long)blockIdx.x * blockDim.x + threadIdx.x;
    long long stride = (long long)gridDim.x * blockDim.x;
    for (; i < n4; i += stride) {
        float4 a = r1[i]; a.x *= dec; a.y *= dec; a.z *= dec; a.w *= dec; n1[i] = a;
        float4 b = r2[i]; b.x *= d2; b.y *= d2; b.z *= d2; b.w *= d2; n2[i] = b;
        float4 c = r3[i]; c.x *= d3; c.y *= d3; c.z *= d3; c.w *= d3; n3[i] = c;
    }
}

__global__ __launch_bounds__(256) void scatter_edges(
    const float* __restrict__ rp0, const float* __restrict__ rp1,
    const float* __restrict__ rp2, const float* __restrict__ times,
    const float* __restrict__ now_time,
    const int* __restrict__ src_ids, const int* __restrict__ dst_ids, int E,
    float* __restrict__ new1, float* __restrict__ new2, float* __restrict__ new3)
{
    int e = blockIdx.x;
    int d = threadIdx.x;
    float tlast = times[E - 1];
    float dec = expf(-WDECAY * (tlast - now_time[0]));
    float d2 = dec * dec;
    float tw = expf(-WDECAY * (tlast - times[e]));
    long long s = src_ids[e];
    long long t = dst_ids[e];
    long long so = s * D + d;
    long long to = t * D + d;
    float a0s = rp0[so], a0t = rp0[to];
    atomicAdd(&new1[so], a0t * tw);
    atomicAdd(&new1[to], a0s * tw);
    float a1s = rp1[so] * dec, a1t = rp1[to] * dec;
    atomicAdd(&new2[so], a1t * tw);
    atomicAdd(&new2[to], a1s * tw);
    float a2s = rp2[so] * d2, a2t = rp2[to] * d2;
    atomicAdd(&new3[so], a2t * tw);
    atomicAdd(&new3[to], a2s * tw);
}

__global__ __launch_bounds__(64) void pair_feature_mlp(
    const float* __restrict__ rp0, const float* __restrict__ new1,
    const float* __restrict__ new2, const float* __restrict__ new3,
    const int* __restrict__ q_src, const int* __restrict__ q_dst,
    const float* __restrict__ w1, const float* __restrict__ b1,
    const float* __restrict__ w2, const float* __restrict__ b2,
    float* __restrict__ out, int B)
{
    __shared__ float proj[8][260];
    __shared__ float feat_s[64];
    __shared__ float h_s[256];

    int b = blockIdx.x;
    int lid = threadIdx.x;
    long long qs = q_src[b];
    long long qd = q_dst[b];

    const float* tabs[4] = {rp0, new1, new2, new3};
    #pragma unroll
    for (int r = 0; r < 4; ++r) {
        const float* tp = tabs[r];
        float4 v = *(const float4*)(tp + qs * D + lid * 4);
        *(float4*)&proj[r][lid * 4] = v;
        float4 w = *(const float4*)(tp + qd * D + lid * 4);
        *(float4*)&proj[r + 4][lid * 4] = w;
    }
    __syncthreads();

    int p = lid >> 3;
    int q = lid & 7;
    float acc = 0.f;
    #pragma unroll 8
    for (int k = 0; k < 64; ++k) {
        float4 a = *(const float4*)&proj[p][4 * k];
        float4 c = *(const float4*)&proj[q][4 * k];
        acc += a.x * c.x + a.y * c.y + a.z * c.z + a.w * c.w;
    }
    feat_s[lid] = log1pf(fmaxf(acc, 0.f));
    __syncthreads();

    float4 hv = *(const float4*)(b1 + 4 * lid);
    #pragma unroll 4
    for (int i = 0; i < 64; ++i) {
        float fv = feat_s[i];
        float4 w = *(const float4*)(w1 + i * 256 + 4 * lid);
        hv.x += fv * w.x; hv.y += fv * w.y; hv.z += fv * w.z; hv.w += fv * w.w;
    }
    *(float4*)&h_s[4 * lid] = make_float4(fmaxf(hv.x, 0.f), fmaxf(hv.y, 0.f),
                                          fmaxf(hv.z, 0.f), fmaxf(hv.w, 0.f));
    __syncthreads();

    float o0 = 0.f, o1 = 0.f, o2 = 0.f, o3 = 0.f;
    #pragma unroll 4
    for (int j = 0; j < 256; j += 4) {
        o0 += h_s[j + 0] * w2[(j + 0) * 64 + lid];
        o1 += h_s[j + 1] * w2[(j + 1) * 64 + lid];
        o2 += h_s[j + 2] * w2[(j + 2) * 64 + lid];
        o3 += h_s[j + 3] * w2[(j + 3) * 64 + lid];
    }
    out[(long long)b * 64 + lid] = b2[lid] + (o0 + o1) + (o2 + o3);
}

extern "C" void kernel_launch(void* const* d_in, const int* in_sizes, int n_in,
                              void* d_out, int out_size, void* d_ws, size_t ws_size,
                              hipStream_t stream)
{
    const float* rp0      = (const float*)d_in[0];
    const float* rp1      = (const float*)d_in[1];
    const float* rp2      = (const float*)d_in[2];
    const float* rp3      = (const float*)d_in[3];
    const float* times    = (const float*)d_in[4];
    const float* now_time = (const float*)d_in[5];
    const float* w1       = (const float*)d_in[6];
    const float* b1       = (const float*)d_in[7];
    const float* w2       = (const float*)d_in[8];
    const float* b2       = (const float*)d_in[9];
    const int*   src_ids  = (const int*)d_in[10];
    const int*   dst_ids  = (const int*)d_in[11];
    const int*   q_src    = (const int*)d_in[12];
    const int*   q_dst    = (const int*)d_in[13];
    float* out = (float*)d_out;

    long long ND = in_sizes[0];      // N * D
    int N = (int)(ND / D);
    int E = in_sizes[4];
    int B = in_sizes[12];
    int NB = (N + CHUNK - 1) / CHUNK;

    float* new1 = (float*)d_ws;
    float* new2 = new1 + ND;
    float* new3 = new2 + ND;

    size_t base_bytes = (size_t)3 * ND * sizeof(float);
    size_t extra_bytes = (size_t)(2 * N + (N + 1) + 2 * E + NB) * sizeof(int)
                       + (size_t)(2 * E) * sizeof(float)
                       + (size_t)B * 64 * sizeof(float);

    if (ws_size >= base_bytes + extra_bytes && NB <= 65536) {
        int* cnt       = (int*)(new3 + ND);           // N (becomes cursor)
        int* flag      = cnt + N;                     // N
        int* row_start = flag + N;                    // N+1
        int* adj_other = row_start + N + 1;           // 2E
        float* adj_tw  = (float*)(adj_other + 2 * E); // 2E
        int* bsum      = (int*)(adj_tw + 2 * E);      // NB
        float* featT   = (float*)(bsum + NB);         // 64*B (transposed)

        hipMemsetAsync(cnt, 0, (size_t)2 * N * sizeof(int), stream);  // cnt + flag
        int twoE = 2 * E;
        hist_kernel<<<(twoE + 255) / 256, 256, 0, stream>>>(src_ids, dst_ids, E, cnt);
        set_flags<<<(B + 255) / 256, 256, 0, stream>>>(q_src, q_dst, B, flag);
        scan_partial<<<NB, 256, 0, stream>>>(cnt, N, bsum);
        scan_blocksums<<<1, 256, 0, stream>>>(bsum, NB, row_start, N);
        scan_apply<<<NB, 256, 0, stream>>>(cnt, bsum, row_start, N);
        fill_kernel<<<(twoE + 255) / 256, 256, 0, stream>>>(src_ids, dst_ids, times, E,
                                                            cnt, adj_other, adj_tw);
        dim3 grid(N, 3);
        apply_updates<<<grid, 64, 0, stream>>>(rp0, rp1, rp2, rp3, times, now_time, E,
                                               row_start, adj_other, adj_tw, flag,
                                               new1, new2, new3);
        gather_gram<<<B, 64, 0, stream>>>(rp0, new1, new2, new3, q_src, q_dst, featT, B);
        mlp_kernel<<<(B + MLP_P - 1) / MLP_P, 256, 0, stream>>>(featT, w1, b1, w2, b2,
                                                                out, B);
    } else {
        long long n4 = ND / 4;
        init_tables<<<2048, 256, 0, stream>>>(rp1, rp2, rp3, times, now_time, E,
                                              new1, new2, new3, n4);
        scatter_edges<<<E, 256, 0, stream>>>(rp0, rp1, rp2, times, now_time,
                                             src_ids, dst_ids, E, new1, new2, new3);
        pair_feature_mlp<<<B, 64, 0, stream>>>(rp0, new1, new2, new3, q_src, q_dst,
                                               w1, b1, w2, b2, out, B);
    }
}

// Round 6
// 643.419 us; speedup vs baseline: 1.0930x; 1.0442x over previous
//
#include <hip/hip_runtime.h>
#include <math.h>

#define D 256
#define WDECAY 1e-6f
#define CHUNK 1024   // elements per scan block (256 threads x 4)
#define MLP_P 64     // pairs per fused-MLP block (fallback path)
#define P1 32        // pairs per mlp1 block
#define P2 32        // pairs per mlp2 block

// ---------------- CSR build ----------------

__global__ __launch_bounds__(256) void hist_kernel(
    const int* __restrict__ src, const int* __restrict__ dst, int E,
    int* __restrict__ cnt)
{
    int i = blockIdx.x * blockDim.x + threadIdx.x;
    if (i < 2 * E) {
        int n = (i < E) ? src[i] : dst[i - E];
        atomicAdd(&cnt[n], 1);
    }
}

__global__ __launch_bounds__(256) void scan_partial(
    const int* __restrict__ cnt, int N, int* __restrict__ bsum)
{
    __shared__ int sdata[256];
    int b = blockIdx.x, t = threadIdx.x;
    int base = b * CHUNK + 4 * t;
    int s = 0;
    if (base + 3 < N) {
        int4 v = *(const int4*)(cnt + base);
        s = v.x + v.y + v.z + v.w;
    } else {
        for (int k = 0; k < 4; ++k)
            if (base + k < N) s += cnt[base + k];
    }
    sdata[t] = s;
    __syncthreads();
    for (int off = 128; off > 0; off >>= 1) {
        if (t < off) sdata[t] += sdata[t + off];
        __syncthreads();
    }
    if (t == 0) bsum[b] = sdata[0];
}

__global__ __launch_bounds__(256) void scan_blocksums(
    int* __restrict__ bsum, int NB, int* __restrict__ row_start, int N)
{
    __shared__ int part[256];
    int t = threadIdx.x;
    int per = (NB + 255) / 256;
    int lo = t * per, hi = lo + per;
    if (hi > NB) hi = NB;
    int s = 0;
    for (int i = lo; i < hi; ++i) s += bsum[i];
    part[t] = s;
    __syncthreads();
    for (int off = 1; off < 256; off <<= 1) {
        int v = (t >= off) ? part[t - off] : 0;
        __syncthreads();
        part[t] += v;
        __syncthreads();
    }
    int base = (t == 0) ? 0 : part[t - 1];
    for (int i = lo; i < hi; ++i) {
        int c = bsum[i];
        bsum[i] = base;
        base += c;
    }
    if (t == 255) row_start[N] = part[255];
}

__global__ __launch_bounds__(256) void scan_apply(
    int* __restrict__ cnt, const int* __restrict__ bsum,
    int* __restrict__ row_start, int N)
{
    __shared__ int part[256];
    int b = blockIdx.x, t = threadIdx.x;
    int base = b * CHUNK + 4 * t;
    int4 v = make_int4(0, 0, 0, 0);
    if (base + 3 < N) {
        v = *(const int4*)(cnt + base);
    } else {
        if (base + 0 < N) v.x = cnt[base + 0];
        if (base + 1 < N) v.y = cnt[base + 1];
        if (base + 2 < N) v.z = cnt[base + 2];
    }
    part[t] = v.x + v.y + v.z + v.w;
    __syncthreads();
    for (int off = 1; off < 256; off <<= 1) {
        int pv = (t >= off) ? part[t - off] : 0;
        __syncthreads();
        part[t] += pv;
        __syncthreads();
    }
    int p = bsum[b] + ((t == 0) ? 0 : part[t - 1]);
    int p0 = p, p1 = p0 + v.x, p2 = p1 + v.y, p3 = p2 + v.z;
    if (base + 0 < N) { row_start[base + 0] = p0; cnt[base + 0] = p0; }
    if (base + 1 < N) { row_start[base + 1] = p1; cnt[base + 1] = p1; }
    if (base + 2 < N) { row_start[base + 2] = p2; cnt[base + 2] = p2; }
    if (base + 3 < N) { row_start[base + 3] = p3; cnt[base + 3] = p3; }
}

__global__ __launch_bounds__(256) void fill_kernel(
    const int* __restrict__ src, const int* __restrict__ dst,
    const float* __restrict__ times, int E,
    int* __restrict__ cursor, int* __restrict__ adj_other,
    float* __restrict__ adj_tw)
{
    int i = blockIdx.x * blockDim.x + threadIdx.x;
    if (i >= 2 * E) return;
    int e = (i < E) ? i : i - E;
    int node  = (i < E) ? src[e] : dst[e];
    int other = (i < E) ? dst[e] : src[e];
    float tlast = times[E - 1];
    float w = expf(-WDECAY * (tlast - times[e]));
    int pos = atomicAdd(&cursor[node], 1);
    adj_other[pos] = other;
    adj_tw[pos] = w;
}

// Mark nodes that appear in any query pair.
__global__ __launch_bounds__(256) void set_flags(
    const int* __restrict__ qs, const int* __restrict__ qd, int B,
    int* __restrict__ flag)
{
    int i = blockIdx.x * blockDim.x + threadIdx.x;
    if (i < B) {
        flag[qs[i]] = 1;
        flag[qd[i]] = 1;
    }
}

// One wave per (node, layer) — R1..R5 A/B: gather BW (~3.85 TB/s) is
// invariant to ILP structure; this TLP-max form is the best measured.
// Do NOT fuse layers or add prefetch depth (tried: 3.3-3.8, all <= this).
__global__ __launch_bounds__(64) void apply_updates(
    const float* __restrict__ rp0, const float* __restrict__ rp1,
    const float* __restrict__ rp2, const float* __restrict__ rp3,
    const float* __restrict__ times, const float* __restrict__ now_time, int E,
    const int* __restrict__ row_start, const int* __restrict__ adj_other,
    const float* __restrict__ adj_tw, const int* __restrict__ flag,
    float* __restrict__ new1, float* __restrict__ new2, float* __restrict__ new3)
{
    int n = blockIdx.x;
    if (!flag[n]) return;          // row never read downstream
    int l = blockIdx.y;
    int lid = threadIdx.x;
    float tlast = times[E - 1];
    float dec = expf(-WDECAY * (tlast - now_time[0]));

    const float* own; const float* gat; float* outp; float os, gs;
    if (l == 0)      { own = rp1; gat = rp0; outp = new1; os = dec;             gs = 1.f;       }
    else if (l == 1) { own = rp2; gat = rp1; outp = new2; os = dec * dec;       gs = dec;       }
    else             { own = rp3; gat = rp2; outp = new3; os = dec * dec * dec; gs = dec * dec; }

    long long base = (long long)n * D + lid * 4;
    float4 acc = *(const float4*)(own + base);
    acc.x *= os; acc.y *= os; acc.z *= os; acc.w *= os;

    int s = row_start[n];
    int e = row_start[n + 1];
    for (int j = s; j < e; ++j) {
        int o = adj_other[j];
        float w = adj_tw[j] * gs;
        float4 v = *(const float4*)(gat + (long long)o * D + lid * 4);
        acc.x += v.x * w; acc.y += v.y * w; acc.z += v.z * w; acc.w += v.w * w;
    }
    *(float4*)(outp + base) = acc;
}

// ---------------- pair feature ----------------

// One wave per pair: gather 8 rows, 8x8 Gram over D=256, log1p.
// Writes feat[b][64] COALESCED (256 B per wave, one cache line) — the
// R1-R5 featT[lid*B+b] layout was a 64-line scatter per wave (~200 MB
// of write-allocate traffic).
__global__ __launch_bounds__(64) void gather_gram(
    const float* __restrict__ rp0, const float* __restrict__ new1,
    const float* __restrict__ new2, const float* __restrict__ new3,
    const int* __restrict__ q_src, const int* __restrict__ q_dst,
    float* __restrict__ feat, int B)
{
    __shared__ float proj[8][260];   // stride 260 -> conflict-free b128
    int b = blockIdx.x;
    int lid = threadIdx.x;
    long long qs = q_src[b];
    long long qd = q_dst[b];

    const float* tabs[4] = {rp0, new1, new2, new3};
    #pragma unroll
    for (int r = 0; r < 4; ++r) {
        const float* tp = tabs[r];
        float4 v = *(const float4*)(tp + qs * D + lid * 4);
        *(float4*)&proj[r][lid * 4] = v;
        float4 w = *(const float4*)(tp + qd * D + lid * 4);
        *(float4*)&proj[r + 4][lid * 4] = w;
    }
    __syncthreads();

    int p = lid >> 3;
    int q = lid & 7;
    float acc = 0.f;
    #pragma unroll 8
    for (int k = 0; k < 64; ++k) {
        float4 a = *(const float4*)&proj[p][4 * k];
        float4 c = *(const float4*)&proj[q][4 * k];
        acc += a.x * c.x + a.y * c.y + a.z * c.z + a.w * c.w;
    }
    feat[(long long)b * 64 + lid] = log1pf(fmaxf(acc, 0.f));
}

// ---------------- MLP split: two streaming GEMMs with real TLP ----------
// mlp1: H = relu(F @ W1 + b1).  W1 (64 KB) + f-tile (9 KB) in LDS ->
// 73 KB => 2 blocks/CU. Weight reads are per-lane float4 (no broadcast
// waste, no strided global). Thread tile 8p x 4o.
__global__ __launch_bounds__(256, 2) void mlp1_kernel(
    const float* __restrict__ feat,    // [B][64]
    const float* __restrict__ w1,      // [64][256] k-major
    const float* __restrict__ b1,      // [256]
    float* __restrict__ H,             // [B][256]
    int B)
{
    __shared__ float w1s[64][256];     // 64 KB, natural layout
    __shared__ float fsT[64][36];      // [k][p], padded, 9 KB
    int t = threadIdx.x;
    int p0 = blockIdx.x * P1;

    // stage W1: 4096 float4 / 256 threads = 16 each (coalesced, conflict-free)
    {
        const float4* wg = (const float4*)w1;
        float4* wd = (float4*)&w1s[0][0];
        #pragma unroll
        for (int r = 0; r < 16; ++r) wd[t + 256 * r] = wg[t + 256 * r];
    }
    // stage f tile transposed: fsT[k][p] = feat[(p0+p)*64 + k]
    // reads coalesced over k; LDS writes 8-way conflict but only 8 instrs.
    #pragma unroll
    for (int r = 0; r < 8; ++r) {
        int idx = t + 256 * r;         // 0..2047 = 32p x 64k
        int p = idx >> 6;
        int k = idx & 63;
        int gp = p0 + p;
        fsT[k][p] = (gp < B) ? feat[(long long)gp * 64 + k] : 0.f;
    }
    __syncthreads();

    int tp = t >> 6;        // 0..3  -> pairs tp*8 .. +7
    int to = t & 63;        // 0..63 -> outs  to*4 .. +3
    float4 acc[8];
    #pragma unroll
    for (int i = 0; i < 8; ++i) acc[i] = make_float4(0.f, 0.f, 0.f, 0.f);

    #pragma unroll 4
    for (int k = 0; k < 64; ++k) {
        float4 fA = *(const float4*)&fsT[k][tp * 8];       // broadcast (1 addr/wave)
        float4 fB = *(const float4*)&fsT[k][tp * 8 + 4];
        float4 wv = *(const float4*)&w1s[k][to * 4];       // per-lane b128
        float f_[8] = {fA.x, fA.y, fA.z, fA.w, fB.x, fB.y, fB.z, fB.w};
        #pragma unroll
        for (int i = 0; i < 8; ++i) {
            acc[i].x += f_[i] * wv.x; acc[i].y += f_[i] * wv.y;
            acc[i].z += f_[i] * wv.z; acc[i].w += f_[i] * wv.w;
        }
    }

    float4 bv = *(const float4*)&b1[to * 4];
    #pragma unroll
    for (int i = 0; i < 8; ++i) {
        int gp = p0 + tp * 8 + i;
        if (gp < B) {
            float4 h = make_float4(fmaxf(acc[i].x + bv.x, 0.f),
                                   fmaxf(acc[i].y + bv.y, 0.f),
                                   fmaxf(acc[i].z + bv.z, 0.f),
                                   fmaxf(acc[i].w + bv.w, 0.f));
            *(float4*)&H[(long long)gp * 256 + to * 4] = h;   // coalesced
        }
    }
}

// mlp2: out = H @ W2 + b2.  H tile (33 KB) in LDS -> 4 blocks/CU;
// W2 streamed from L1/L2 (64 KB, hot). Thread tile 2p x 4c, k by 4.
__global__ __launch_bounds__(256, 2) void mlp2_kernel(
    const float* __restrict__ H,       // [B][256]
    const float* __restrict__ w2,      // [256][64]
    const float* __restrict__ b2,      // [64]
    float* __restrict__ out, int B)
{
    __shared__ float Hs[P2][260];      // 33.3 KB
    int t = threadIdx.x;
    int p0 = blockIdx.x * P2;

    // stage H tile: 32p x 256k = 2048 float4 / 256 threads = 8 each
    #pragma unroll
    for (int r = 0; r < 8; ++r) {
        int idx = t + 256 * r;         // p = idx>>6, k4 = idx&63
        int p = idx >> 6;
        int k4 = idx & 63;
        int gp = p0 + p;
        float4 v = (gp < B) ? *(const float4*)&H[(long long)gp * 256 + k4 * 4]
                            : make_float4(0.f, 0.f, 0.f, 0.f);
        *(float4*)&Hs[p][k4 * 4] = v;
    }
    __syncthreads();

    int tp2 = t >> 4;       // 0..15 -> pairs tp2*2 .. +1
    int tc  = t & 15;       // 0..15 -> cols  tc*4 .. +3
    float4 a0 = make_float4(0.f, 0.f, 0.f, 0.f);
    float4 a1 = make_float4(0.f, 0.f, 0.f, 0.f);

    #pragma unroll 2
    for (int k = 0; k < 256; k += 4) {
        float4 h0 = *(const float4*)&Hs[tp2 * 2 + 0][k];   // few-addr broadcast
        float4 h1 = *(const float4*)&Hs[tp2 * 2 + 1][k];
        float4 w0 = *(const float4*)&w2[(k + 0) * 64 + tc * 4];
        float4 w1v = *(const float4*)&w2[(k + 1) * 64 + tc * 4];
        float4 w2v = *(const float4*)&w2[(k + 2) * 64 + tc * 4];
        float4 w3 = *(const float4*)&w2[(k + 3) * 64 + tc * 4];
        a0.x += h0.x * w0.x + h0.y * w1v.x + h0.z * w2v.x + h0.w * w3.x;
        a0.y += h0.x * w0.y + h0.y * w1v.y + h0.z * w2v.y + h0.w * w3.y;
        a0.z += h0.x * w0.z + h0.y * w1v.z + h0.z * w2v.z + h0.w * w3.z;
        a0.w += h0.x * w0.w + h0.y * w1v.w + h0.z * w2v.w + h0.w * w3.w;
        a1.x += h1.x * w0.x + h1.y * w1v.x + h1.z * w2v.x + h1.w * w3.x;
        a1.y += h1.x * w0.y + h1.y * w1v.y + h1.z * w2v.y + h1.w * w3.y;
        a1.z += h1.x * w0.z + h1.y * w1v.z + h1.z * w2v.z + h1.w * w3.z;
        a1.w += h1.x * w0.w + h1.y * w1v.w + h1.z * w2v.w + h1.w * w3.w;
    }

    float4 bv = *(const float4*)&b2[tc * 4];
    int gp0 = p0 + tp2 * 2;
    if (gp0 < B)
        *(float4*)&out[(long long)gp0 * 64 + tc * 4] =
            make_float4(a0.x + bv.x, a0.y + bv.y, a0.z + bv.z, a0.w + bv.w);
    if (gp0 + 1 < B)
        *(float4*)&out[(long long)(gp0 + 1) * 64 + tc * 4] =
            make_float4(a1.x + bv.x, a1.y + bv.y, a1.z + bv.z, a1.w + bv.w);
}

// Fused single-kernel MLP (used only if workspace can't hold H).
__global__ __launch_bounds__(256, 1) void mlp_fused(
    const float* __restrict__ feat,    // [B][64]
    const float* __restrict__ w1,      // [64][256]
    const float* __restrict__ b1,
    const float* __restrict__ w2,      // [256][64]
    const float* __restrict__ b2,
    float* __restrict__ out, int B)
{
    __shared__ float fsT[64][68];      // [k][p]
    __shared__ float w1s[64 * 256];    // 64 KB
    __shared__ float hT[256][65];
    int t = threadIdx.x;
    int p0 = blockIdx.x * MLP_P;

    {
        const float4* wg = (const float4*)w1;
        float4* wd = (float4*)w1s;
        #pragma unroll
        for (int r = 0; r < 16; ++r) wd[t + 256 * r] = wg[t + 256 * r];
    }
    #pragma unroll
    for (int r = 0; r < 16; ++r) {
        int idx = t + 256 * r;         // 64p x 64k
        int p = idx >> 6;
        int k = idx & 63;
        int gp = p0 + p;
        fsT[k][p] = (gp < B) ? feat[(long long)gp * 64 + k] : 0.f;
    }
    __syncthreads();

    {
        int tp = t >> 5;          // 0..7
        int to = t & 31;          // 0..31
        float acc[8][8];
        #pragma unroll
        for (int i = 0; i < 8; ++i)
            #pragma unroll
            for (int j = 0; j < 8; ++j) acc[i][j] = 0.f;

        #pragma unroll 4
        for (int k = 0; k < 64; ++k) {
            float4 fA = *(const float4*)&fsT[k][tp * 8];
            float4 fB = *(const float4*)&fsT[k][tp * 8 + 4];
            const float* wr = w1s + k * 256 + to;
            float w[8];
            #pragma unroll
            for (int j = 0; j < 8; ++j) w[j] = wr[32 * j];
            float f0 = fA.x, f1 = fA.y, f2 = fA.z, f3 = fA.w;
            float f4 = fB.x, f5 = fB.y, f6 = fB.z, f7 = fB.w;
            #pragma unroll
            for (int j = 0; j < 8; ++j) {
                acc[0][j] += f0 * w[j]; acc[1][j] += f1 * w[j];
                acc[2][j] += f2 * w[j]; acc[3][j] += f3 * w[j];
                acc[4][j] += f4 * w[j]; acc[5][j] += f5 * w[j];
                acc[6][j] += f6 * w[j]; acc[7][j] += f7 * w[j];
            }
        }
        #pragma unroll
        for (int j = 0; j < 8; ++j) {
            int o = to + 32 * j;
            float bb = b1[o];
            #pragma unroll
            for (int i = 0; i < 8; ++i)
                hT[o][tp * 8 + i] = fmaxf(acc[i][j] + bb, 0.f);
        }
    }
    __syncthreads();

    {
        int tp2 = t >> 4;
        int tc  = t & 15;
        float a0x = 0.f, a0y = 0.f, a0z = 0.f, a0w = 0.f;
        float a1x = 0.f, a1y = 0.f, a1z = 0.f, a1w = 0.f;
        float a2x = 0.f, a2y = 0.f, a2z = 0.f, a2w = 0.f;
        float a3x = 0.f, a3y = 0.f, a3z = 0.f, a3w = 0.f;

        #pragma unroll 8
        for (int k = 0; k < 256; ++k) {
            float h0 = hT[k][tp2 * 4 + 0];
            float h1 = hT[k][tp2 * 4 + 1];
            float h2 = hT[k][tp2 * 4 + 2];
            float h3 = hT[k][tp2 * 4 + 3];
            float4 wv = *(const float4*)&w2[k * 64 + tc * 4];
            a0x += h0 * wv.x; a0y += h0 * wv.y; a0z += h0 * wv.z; a0w += h0 * wv.w;
            a1x += h1 * wv.x; a1y += h1 * wv.y; a1z += h1 * wv.z; a1w += h1 * wv.w;
            a2x += h2 * wv.x; a2y += h2 * wv.y; a2z += h2 * wv.z; a2w += h2 * wv.w;
            a3x += h3 * wv.x; a3y += h3 * wv.y; a3z += h3 * wv.z; a3w += h3 * wv.w;
        }
        float4 bv = *(const float4*)&b2[tc * 4];
        int gp = p0 + tp2 * 4;
        float* op = out + (long long)gp * 64 + tc * 4;
        if (gp + 0 < B) *(float4*)(op + 0 * 64) =
            make_float4(a0x + bv.x, a0y + bv.y, a0z + bv.z, a0w + bv.w);
        if (gp + 1 < B) *(float4*)(op + 1 * 64) =
            make_float4(a1x + bv.x, a1y + bv.y, a1z + bv.z, a1w + bv.w);
        if (gp + 2 < B) *(float4*)(op + 2 * 64) =
            make_float4(a2x + bv.x, a2y + bv.y, a2z + bv.z, a2w + bv.w);
        if (gp + 3 < B) *(float4*)(op + 3 * 64) =
            make_float4(a3x + bv.x, a3y + bv.y, a3z + bv.z, a3w + bv.w);
    }
}

// ---------------- fallback (atomic) path ----------------

__global__ __launch_bounds__(256) void init_tables(
    const float* __restrict__ rp1, const float* __restrict__ rp2,
    const float* __restrict__ rp3, const float* __restrict__ times,
    const float* __restrict__ now_time, int E,
    float* __restrict__ new1, float* __restrict__ new2, float* __restrict__ new3,
    long long n4)
{
    float tlast = times[E - 1];
    float dec = expf(-WDECAY * (tlast - now_time[0]));
    float d2 = dec * dec;
    float d3 = d2 * dec;
    const float4* r1 = (const float4*)rp1;
    const float4* r2 = (const float4*)rp2;
    const float4* r3 = (const float4*)rp3;
    float4* n1 = (float4*)new1;
    float4* n2 = (float4*)new2;
    float4* n3 = (float4*)new3;
    long long i = (long long)blockIdx.x * blockDim.x + threadIdx.x;
    long long stride = (long long)gridDim.x * blockDim.x;
    for (; i < n4; i += stride) {
        float4 a = r1[i]; a.x *= dec; a.y *= dec; a.z *= dec; a.w *= dec; n1[i] = a;
        float4 b = r2[i]; b.x *= d2; b.y *= d2; b.z *= d2; b.w *= d2; n2[i] = b;
        float4 c = r3[i]; c.x *= d3; c.y *= d3; c.z *= d3; c.w *= d3; n3[i] = c;
    }
}

__global__ __launch_bounds__(256) void scatter_edges(
    const float* __restrict__ rp0, const float* __restrict__ rp1,
    const float* __restrict__ rp2, const float* __restrict__ times,
    const float* __restrict__ now_time,
    const int* __restrict__ src_ids, const int* __restrict__ dst_ids, int E,
    float* __restrict__ new1, float* __restrict__ new2, float* __restrict__ new3)
{
    int e = blockIdx.x;
    int d = threadIdx.x;
    float tlast = times[E - 1];
    float dec = expf(-WDECAY * (tlast - now_time[0]));
    float d2 = dec * dec;
    float tw = expf(-WDECAY * (tlast - times[e]));
    long long s = src_ids[e];
    long long t = dst_ids[e];
    long long so = s * D + d;
    long long to = t * D + d;
    float a0s = rp0[so], a0t = rp0[to];
    atomicAdd(&new1[so], a0t * tw);
    atomicAdd(&new1[to], a0s * tw);
    float a1s = rp1[so] * dec, a1t = rp1[to] * dec;
    atomicAdd(&new2[so], a1t * tw);
    atomicAdd(&new2[to], a1s * tw);
    float a2s = rp2[so] * d2, a2t = rp2[to] * d2;
    atomicAdd(&new3[so], a2t * tw);
    atomicAdd(&new3[to], a2s * tw);
}

__global__ __launch_bounds__(64) void pair_feature_mlp(
    const float* __restrict__ rp0, const float* __restrict__ new1,
    const float* __restrict__ new2, const float* __restrict__ new3,
    const int* __restrict__ q_src, const int* __restrict__ q_dst,
    const float* __restrict__ w1, const float* __restrict__ b1,
    const float* __restrict__ w2, const float* __restrict__ b2,
    float* __restrict__ out, int B)
{
    __shared__ float proj[8][260];
    __shared__ float feat_s[64];
    __shared__ float h_s[256];

    int b = blockIdx.x;
    int lid = threadIdx.x;
    long long qs = q_src[b];
    long long qd = q_dst[b];

    const float* tabs[4] = {rp0, new1, new2, new3};
    #pragma unroll
    for (int r = 0; r < 4; ++r) {
        const float* tp = tabs[r];
        float4 v = *(const float4*)(tp + qs * D + lid * 4);
        *(float4*)&proj[r][lid * 4] = v;
        float4 w = *(const float4*)(tp + qd * D + lid * 4);
        *(float4*)&proj[r + 4][lid * 4] = w;
    }
    __syncthreads();

    int p = lid >> 3;
    int q = lid & 7;
    float acc = 0.f;
    #pragma unroll 8
    for (int k = 0; k < 64; ++k) {
        float4 a = *(const float4*)&proj[p][4 * k];
        float4 c = *(const float4*)&proj[q][4 * k];
        acc += a.x * c.x + a.y * c.y + a.z * c.z + a.w * c.w;
    }
    feat_s[lid] = log1pf(fmaxf(acc, 0.f));
    __syncthreads();

    float4 hv = *(const float4*)(b1 + 4 * lid);
    #pragma unroll 4
    for (int i = 0; i < 64; ++i) {
        float fv = feat_s[i];
        float4 w = *(const float4*)(w1 + i * 256 + 4 * lid);
        hv.x += fv * w.x; hv.y += fv * w.y; hv.z += fv * w.z; hv.w += fv * w.w;
    }
    *(float4*)&h_s[4 * lid] = make_float4(fmaxf(hv.x, 0.f), fmaxf(hv.y, 0.f),
                                          fmaxf(hv.z, 0.f), fmaxf(hv.w, 0.f));
    __syncthreads();

    float o0 = 0.f, o1 = 0.f, o2 = 0.f, o3 = 0.f;
    #pragma unroll 4
    for (int j = 0; j < 256; j += 4) {
        o0 += h_s[j + 0] * w2[(j + 0) * 64 + lid];
        o1 += h_s[j + 1] * w2[(j + 1) * 64 + lid];
        o2 += h_s[j + 2] * w2[(j + 2) * 64 + lid];
        o3 += h_s[j + 3] * w2[(j + 3) * 64 + lid];
    }
    out[(long long)b * 64 + lid] = b2[lid] + (o0 + o1) + (o2 + o3);
}

extern "C" void kernel_launch(void* const* d_in, const int* in_sizes, int n_in,
                              void* d_out, int out_size, void* d_ws, size_t ws_size,
                              hipStream_t stream)
{
    const float* rp0      = (const float*)d_in[0];
    const float* rp1      = (const float*)d_in[1];
    const float* rp2      = (const float*)d_in[2];
    const float* rp3      = (const float*)d_in[3];
    const float* times    = (const float*)d_in[4];
    const float* now_time = (const float*)d_in[5];
    const float* w1       = (const float*)d_in[6];
    const float* b1       = (const float*)d_in[7];
    const float* w2       = (const float*)d_in[8];
    const float* b2       = (const float*)d_in[9];
    const int*   src_ids  = (const int*)d_in[10];
    const int*   dst_ids  = (const int*)d_in[11];
    const int*   q_src    = (const int*)d_in[12];
    const int*   q_dst    = (const int*)d_in[13];
    float* out = (float*)d_out;

    long long ND = in_sizes[0];      // N * D
    int N = (int)(ND / D);
    int E = in_sizes[4];
    int B = in_sizes[12];
    int NB = (N + CHUNK - 1) / CHUNK;

    float* new1 = (float*)d_ws;
    float* new2 = new1 + ND;
    float* new3 = new2 + ND;

    size_t base_bytes = (size_t)3 * ND * sizeof(float);
    size_t csr_bytes  = (size_t)(2 * N + (N + 1) + 2 * E + NB) * sizeof(int)
                      + (size_t)(2 * E) * sizeof(float)
                      + (size_t)B * 64 * sizeof(float);
    size_t h_bytes    = (size_t)B * 256 * sizeof(float);

    if (ws_size >= base_bytes + csr_bytes && NB <= 65536) {
        int* cnt       = (int*)(new3 + ND);           // N (becomes cursor)
        int* flag      = cnt + N;                     // N
        int* row_start = flag + N;                    // N+1
        int* adj_other = row_start + N + 1;           // 2E
        float* adj_tw  = (float*)(adj_other + 2 * E); // 2E
        int* bsum      = (int*)(adj_tw + 2 * E);      // NB
        float* feat    = (float*)(bsum + NB);         // B*64
        float* Hbuf    = feat + (size_t)B * 64;       // B*256 (if it fits)
        bool   split   = (ws_size >= base_bytes + csr_bytes + h_bytes);

        hipMemsetAsync(cnt, 0, (size_t)2 * N * sizeof(int), stream);  // cnt + flag
        int twoE = 2 * E;
        hist_kernel<<<(twoE + 255) / 256, 256, 0, stream>>>(src_ids, dst_ids, E, cnt);
        set_flags<<<(B + 255) / 256, 256, 0, stream>>>(q_src, q_dst, B, flag);
        scan_partial<<<NB, 256, 0, stream>>>(cnt, N, bsum);
        scan_blocksums<<<1, 256, 0, stream>>>(bsum, NB, row_start, N);
        scan_apply<<<NB, 256, 0, stream>>>(cnt, bsum, row_start, N);
        fill_kernel<<<(twoE + 255) / 256, 256, 0, stream>>>(src_ids, dst_ids, times, E,
                                                            cnt, adj_other, adj_tw);
        dim3 grid(N, 3);
        apply_updates<<<grid, 64, 0, stream>>>(rp0, rp1, rp2, rp3, times, now_time, E,
                                               row_start, adj_other, adj_tw, flag,
                                               new1, new2, new3);
        gather_gram<<<B, 64, 0, stream>>>(rp0, new1, new2, new3, q_src, q_dst, feat, B);
        if (split) {
            mlp1_kernel<<<(B + P1 - 1) / P1, 256, 0, stream>>>(feat, w1, b1, Hbuf, B);
            mlp2_kernel<<<(B + P2 - 1) / P2, 256, 0, stream>>>(Hbuf, w2, b2, out, B);
        } else {
            mlp_fused<<<(B + MLP_P - 1) / MLP_P, 256, 0, stream>>>(feat, w1, b1, w2, b2,
                                                                   out, B);
        }
    } else {
        long long n4 = ND / 4;
        init_tables<<<2048, 256, 0, stream>>>(rp1, rp2, rp3, times, now_time, E,
                                              new1, new2, new3, n4);
        scatter_edges<<<E, 256, 0, stream>>>(rp0, rp1, rp2, times, now_time,
                                             src_ids, dst_ids, E, new1, new2, new3);
        pair_feature_mlp<<<B, 64, 0, stream>>>(rp0, new1, new2, new3, q_src, q_dst,
                                               w1, b1, w2, b2, out, B);
    }
}

// Round 7
// 641.207 us; speedup vs baseline: 1.0968x; 1.0035x over previous
//
#include <hip/hip_runtime.h>
#include <math.h>

#define D 256
#define WDECAY 1e-6f
#define CHUNK 1024   // elements per scan block (256 threads x 4)
#define MLP_P 64     // pairs per fused-MLP block (fallback path)
#define P1 32        // pairs per mlp1 block
#define P2 32        // pairs per mlp2 block

// ---------------- CSR build ----------------

__global__ __launch_bounds__(256) void hist_kernel(
    const int* __restrict__ src, const int* __restrict__ dst, int E,
    int* __restrict__ cnt)
{
    int i = blockIdx.x * blockDim.x + threadIdx.x;
    if (i < 2 * E) {
        int n = (i < E) ? src[i] : dst[i - E];
        atomicAdd(&cnt[n], 1);
    }
}

__global__ __launch_bounds__(256) void scan_partial(
    const int* __restrict__ cnt, int N, int* __restrict__ bsum)
{
    __shared__ int sdata[256];
    int b = blockIdx.x, t = threadIdx.x;
    int base = b * CHUNK + 4 * t;
    int s = 0;
    if (base + 3 < N) {
        int4 v = *(const int4*)(cnt + base);
        s = v.x + v.y + v.z + v.w;
    } else {
        for (int k = 0; k < 4; ++k)
            if (base + k < N) s += cnt[base + k];
    }
    sdata[t] = s;
    __syncthreads();
    for (int off = 128; off > 0; off >>= 1) {
        if (t < off) sdata[t] += sdata[t + off];
        __syncthreads();
    }
    if (t == 0) bsum[b] = sdata[0];
}

__global__ __launch_bounds__(256) void scan_blocksums(
    int* __restrict__ bsum, int NB, int* __restrict__ row_start, int N)
{
    __shared__ int part[256];
    int t = threadIdx.x;
    int per = (NB + 255) / 256;
    int lo = t * per, hi = lo + per;
    if (hi > NB) hi = NB;
    int s = 0;
    for (int i = lo; i < hi; ++i) s += bsum[i];
    part[t] = s;
    __syncthreads();
    for (int off = 1; off < 256; off <<= 1) {
        int v = (t >= off) ? part[t - off] : 0;
        __syncthreads();
        part[t] += v;
        __syncthreads();
    }
    int base = (t == 0) ? 0 : part[t - 1];
    for (int i = lo; i < hi; ++i) {
        int c = bsum[i];
        bsum[i] = base;
        base += c;
    }
    if (t == 255) row_start[N] = part[255];
}

__global__ __launch_bounds__(256) void scan_apply(
    int* __restrict__ cnt, const int* __restrict__ bsum,
    int* __restrict__ row_start, int N)
{
    __shared__ int part[256];
    int b = blockIdx.x, t = threadIdx.x;
    int base = b * CHUNK + 4 * t;
    int4 v = make_int4(0, 0, 0, 0);
    if (base + 3 < N) {
        v = *(const int4*)(cnt + base);
    } else {
        if (base + 0 < N) v.x = cnt[base + 0];
        if (base + 1 < N) v.y = cnt[base + 1];
        if (base + 2 < N) v.z = cnt[base + 2];
    }
    part[t] = v.x + v.y + v.z + v.w;
    __syncthreads();
    for (int off = 1; off < 256; off <<= 1) {
        int pv = (t >= off) ? part[t - off] : 0;
        __syncthreads();
        part[t] += pv;
        __syncthreads();
    }
    int p = bsum[b] + ((t == 0) ? 0 : part[t - 1]);
    int p0 = p, p1 = p0 + v.x, p2 = p1 + v.y, p3 = p2 + v.z;
    if (base + 0 < N) { row_start[base + 0] = p0; cnt[base + 0] = p0; }
    if (base + 1 < N) { row_start[base + 1] = p1; cnt[base + 1] = p1; }
    if (base + 2 < N) { row_start[base + 2] = p2; cnt[base + 2] = p2; }
    if (base + 3 < N) { row_start[base + 3] = p3; cnt[base + 3] = p3; }
}

__global__ __launch_bounds__(256) void fill_kernel(
    const int* __restrict__ src, const int* __restrict__ dst,
    const float* __restrict__ times, int E,
    int* __restrict__ cursor, int* __restrict__ adj_other,
    float* __restrict__ adj_tw)
{
    int i = blockIdx.x * blockDim.x + threadIdx.x;
    if (i >= 2 * E) return;
    int e = (i < E) ? i : i - E;
    int node  = (i < E) ? src[e] : dst[e];
    int other = (i < E) ? dst[e] : src[e];
    float tlast = times[E - 1];
    float w = expf(-WDECAY * (tlast - times[e]));
    int pos = atomicAdd(&cursor[node], 1);
    adj_other[pos] = other;
    adj_tw[pos] = w;
}

// Mark nodes that appear in any query pair.
__global__ __launch_bounds__(256) void set_flags(
    const int* __restrict__ qs, const int* __restrict__ qd, int B,
    int* __restrict__ flag)
{
    int i = blockIdx.x * blockDim.x + threadIdx.x;
    if (i < B) {
        flag[qs[i]] = 1;
        flag[qd[i]] = 1;
    }
}

// One wave per (node, layer) — R1..R5 A/B: gather BW (~3.85 TB/s) is
// invariant to ILP structure; this TLP-max form is the best measured.
// Do NOT fuse layers or add prefetch depth (tried: 3.3-3.8, all <= this).
__global__ __launch_bounds__(64) void apply_updates(
    const float* __restrict__ rp0, const float* __restrict__ rp1,
    const float* __restrict__ rp2, const float* __restrict__ rp3,
    const float* __restrict__ times, const float* __restrict__ now_time, int E,
    const int* __restrict__ row_start, const int* __restrict__ adj_other,
    const float* __restrict__ adj_tw, const int* __restrict__ flag,
    float* __restrict__ new1, float* __restrict__ new2, float* __restrict__ new3)
{
    int n = blockIdx.x;
    if (!flag[n]) return;          // row never read downstream
    int l = blockIdx.y;
    int lid = threadIdx.x;
    float tlast = times[E - 1];
    float dec = expf(-WDECAY * (tlast - now_time[0]));

    const float* own; const float* gat; float* outp; float os, gs;
    if (l == 0)      { own = rp1; gat = rp0; outp = new1; os = dec;             gs = 1.f;       }
    else if (l == 1) { own = rp2; gat = rp1; outp = new2; os = dec * dec;       gs = dec;       }
    else             { own = rp3; gat = rp2; outp = new3; os = dec * dec * dec; gs = dec * dec; }

    long long base = (long long)n * D + lid * 4;
    float4 acc = *(const float4*)(own + base);
    acc.x *= os; acc.y *= os; acc.z *= os; acc.w *= os;

    int s = row_start[n];
    int e = row_start[n + 1];
    for (int j = s; j < e; ++j) {
        int o = adj_other[j];
        float w = adj_tw[j] * gs;
        float4 v = *(const float4*)(gat + (long long)o * D + lid * 4);
        acc.x += v.x * w; acc.y += v.y * w; acc.z += v.z * w; acc.w += v.w * w;
    }
    *(float4*)(outp + base) = acc;
}

// ---------------- pair feature ----------------

// Register-resident Gram: the 8 gathered float4s per lane ARE the operands
// (lane lid holds d-slice [4*lid, 4*lid+4) of all 8 rows). Compute 64
// per-lane partial dots (36 unique, mirrored), then a 6-level recursive-
// halving butterfly (__shfl_xor 32,16,8,4,2,1 = 63 DS ops) leaves lane l
// holding Gram cell l. Replaces the R6 LDS version's 136 ds_read_b128 +
// __syncthreads per wave (DS-pipe serialized at ~16 waves/CU).
__global__ __launch_bounds__(256) void gather_gram(
    const float* __restrict__ rp0, const float* __restrict__ new1,
    const float* __restrict__ new2, const float* __restrict__ new3,
    const int* __restrict__ q_src, const int* __restrict__ q_dst,
    float* __restrict__ feat, int B)
{
    int b = blockIdx.x * 4 + (threadIdx.x >> 6);   // 4 independent waves/block
    int lid = threadIdx.x & 63;
    if (b >= B) return;                            // wave-uniform exit
    long long qs = q_src[b];
    long long qd = q_dst[b];

    const float* tabs[4] = {rp0, new1, new2, new3};
    float4 v[8];
    #pragma unroll
    for (int r = 0; r < 4; ++r) {
        v[r]     = *(const float4*)(tabs[r] + qs * D + lid * 4);
        v[r + 4] = *(const float4*)(tabs[r] + qd * D + lid * 4);
    }

    // per-lane partials for all 64 cells (symmetric: 36 dots)
    float red[64];
    #pragma unroll
    for (int p = 0; p < 8; ++p) {
        #pragma unroll
        for (int q = p; q < 8; ++q) {
            float d = v[p].x * v[q].x + v[p].y * v[q].y
                    + v[p].z * v[q].z + v[p].w * v[q].w;
            red[p * 8 + q] = d;
            red[q * 8 + p] = d;
        }
    }

    // butterfly reduce-scatter: after 6 levels lane l holds sum over all
    // lanes of partial[cell == l]. At each level, keep cells whose bit
    // matches the lane's bit; exchange the other half.
    {
        bool hi = (lid & 32) != 0;
        #pragma unroll
        for (int i = 0; i < 32; ++i) {
            float send = hi ? red[i] : red[i + 32];
            float keep = hi ? red[i + 32] : red[i];
            red[i] = keep + __shfl_xor(send, 32, 64);
        }
    }
    {
        bool hi = (lid & 16) != 0;
        #pragma unroll
        for (int i = 0; i < 16; ++i) {
            float send = hi ? red[i] : red[i + 16];
            float keep = hi ? red[i + 16] : red[i];
            red[i] = keep + __shfl_xor(send, 16, 64);
        }
    }
    {
        bool hi = (lid & 8) != 0;
        #pragma unroll
        for (int i = 0; i < 8; ++i) {
            float send = hi ? red[i] : red[i + 8];
            float keep = hi ? red[i + 8] : red[i];
            red[i] = keep + __shfl_xor(send, 8, 64);
        }
    }
    {
        bool hi = (lid & 4) != 0;
        #pragma unroll
        for (int i = 0; i < 4; ++i) {
            float send = hi ? red[i] : red[i + 4];
            float keep = hi ? red[i + 4] : red[i];
            red[i] = keep + __shfl_xor(send, 4, 64);
        }
    }
    {
        bool hi = (lid & 2) != 0;
        #pragma unroll
        for (int i = 0; i < 2; ++i) {
            float send = hi ? red[i] : red[i + 2];
            float keep = hi ? red[i + 2] : red[i];
            red[i] = keep + __shfl_xor(send, 2, 64);
        }
    }
    {
        bool hi = (lid & 1) != 0;
        float send = hi ? red[0] : red[1];
        float keep = hi ? red[1] : red[0];
        red[0] = keep + __shfl_xor(send, 1, 64);
    }

    feat[(long long)b * 64 + lid] = log1pf(fmaxf(red[0], 0.f));
}

// ---------------- MLP split: two streaming GEMMs with real TLP ----------
// mlp1: H = relu(F @ W1 + b1).  W1 (64 KB) + f-tile (9 KB) in LDS ->
// 73 KB => 2 blocks/CU. Weight reads are per-lane float4 (no broadcast
// waste, no strided global). Thread tile 8p x 4o.
__global__ __launch_bounds__(256, 2) void mlp1_kernel(
    const float* __restrict__ feat,    // [B][64]
    const float* __restrict__ w1,      // [64][256] k-major
    const float* __restrict__ b1,      // [256]
    float* __restrict__ H,             // [B][256]
    int B)
{
    __shared__ float w1s[64][256];     // 64 KB, natural layout
    __shared__ float fsT[64][36];      // [k][p], padded, 9 KB
    int t = threadIdx.x;
    int p0 = blockIdx.x * P1;

    // stage W1: 4096 float4 / 256 threads = 16 each (coalesced, conflict-free)
    {
        const float4* wg = (const float4*)w1;
        float4* wd = (float4*)&w1s[0][0];
        #pragma unroll
        for (int r = 0; r < 16; ++r) wd[t + 256 * r] = wg[t + 256 * r];
    }
    // stage f tile transposed: fsT[k][p] = feat[(p0+p)*64 + k]
    #pragma unroll
    for (int r = 0; r < 8; ++r) {
        int idx = t + 256 * r;         // 0..2047 = 32p x 64k
        int p = idx >> 6;
        int k = idx & 63;
        int gp = p0 + p;
        fsT[k][p] = (gp < B) ? feat[(long long)gp * 64 + k] : 0.f;
    }
    __syncthreads();

    int tp = t >> 6;        // 0..3  -> pairs tp*8 .. +7
    int to = t & 63;        // 0..63 -> outs  to*4 .. +3
    float4 acc[8];
    #pragma unroll
    for (int i = 0; i < 8; ++i) acc[i] = make_float4(0.f, 0.f, 0.f, 0.f);

    #pragma unroll 4
    for (int k = 0; k < 64; ++k) {
        float4 fA = *(const float4*)&fsT[k][tp * 8];       // broadcast
        float4 fB = *(const float4*)&fsT[k][tp * 8 + 4];
        float4 wv = *(const float4*)&w1s[k][to * 4];       // per-lane b128
        float f_[8] = {fA.x, fA.y, fA.z, fA.w, fB.x, fB.y, fB.z, fB.w};
        #pragma unroll
        for (int i = 0; i < 8; ++i) {
            acc[i].x += f_[i] * wv.x; acc[i].y += f_[i] * wv.y;
            acc[i].z += f_[i] * wv.z; acc[i].w += f_[i] * wv.w;
        }
    }

    float4 bv = *(const float4*)&b1[to * 4];
    #pragma unroll
    for (int i = 0; i < 8; ++i) {
        int gp = p0 + tp * 8 + i;
        if (gp < B) {
            float4 h = make_float4(fmaxf(acc[i].x + bv.x, 0.f),
                                   fmaxf(acc[i].y + bv.y, 0.f),
                                   fmaxf(acc[i].z + bv.z, 0.f),
                                   fmaxf(acc[i].w + bv.w, 0.f));
            *(float4*)&H[(long long)gp * 256 + to * 4] = h;   // coalesced
        }
    }
}

// mlp2: out = H @ W2 + b2.  H tile (33 KB) in LDS -> 2 blocks/CU;
// W2 streamed from L1/L2 (64 KB, hot). Thread tile 2p x 4c, k by 4.
__global__ __launch_bounds__(256, 2) void mlp2_kernel(
    const float* __restrict__ H,       // [B][256]
    const float* __restrict__ w2,      // [256][64]
    const float* __restrict__ b2,      // [64]
    float* __restrict__ out, int B)
{
    __shared__ float Hs[P2][260];      // 33.3 KB
    int t = threadIdx.x;
    int p0 = blockIdx.x * P2;

    // stage H tile: 32p x 256k = 2048 float4 / 256 threads = 8 each
    #pragma unroll
    for (int r = 0; r < 8; ++r) {
        int idx = t + 256 * r;         // p = idx>>6, k4 = idx&63
        int p = idx >> 6;
        int k4 = idx & 63;
        int gp = p0 + p;
        float4 v = (gp < B) ? *(const float4*)&H[(long long)gp * 256 + k4 * 4]
                            : make_float4(0.f, 0.f, 0.f, 0.f);
        *(float4*)&Hs[p][k4 * 4] = v;
    }
    __syncthreads();

    int tp2 = t >> 4;       // 0..15 -> pairs tp2*2 .. +1
    int tc  = t & 15;       // 0..15 -> cols  tc*4 .. +3
    float4 a0 = make_float4(0.f, 0.f, 0.f, 0.f);
    float4 a1 = make_float4(0.f, 0.f, 0.f, 0.f);

    #pragma unroll 2
    for (int k = 0; k < 256; k += 4) {
        float4 h0 = *(const float4*)&Hs[tp2 * 2 + 0][k];
        float4 h1 = *(const float4*)&Hs[tp2 * 2 + 1][k];
        float4 w0 = *(const float4*)&w2[(k + 0) * 64 + tc * 4];
        float4 w1v = *(const float4*)&w2[(k + 1) * 64 + tc * 4];
        float4 w2v = *(const float4*)&w2[(k + 2) * 64 + tc * 4];
        float4 w3 = *(const float4*)&w2[(k + 3) * 64 + tc * 4];
        a0.x += h0.x * w0.x + h0.y * w1v.x + h0.z * w2v.x + h0.w * w3.x;
        a0.y += h0.x * w0.y + h0.y * w1v.y + h0.z * w2v.y + h0.w * w3.y;
        a0.z += h0.x * w0.z + h0.y * w1v.z + h0.z * w2v.z + h0.w * w3.z;
        a0.w += h0.x * w0.w + h0.y * w1v.w + h0.z * w2v.w + h0.w * w3.w;
        a1.x += h1.x * w0.x + h1.y * w1v.x + h1.z * w2v.x + h1.w * w3.x;
        a1.y += h1.x * w0.y + h1.y * w1v.y + h1.z * w2v.y + h1.w * w3.y;
        a1.z += h1.x * w0.z + h1.y * w1v.z + h1.z * w2v.z + h1.w * w3.z;
        a1.w += h1.x * w0.w + h1.y * w1v.w + h1.z * w2v.w + h1.w * w3.w;
    }

    float4 bv = *(const float4*)&b2[tc * 4];
    int gp0 = p0 + tp2 * 2;
    if (gp0 < B)
        *(float4*)&out[(long long)gp0 * 64 + tc * 4] =
            make_float4(a0.x + bv.x, a0.y + bv.y, a0.z + bv.z, a0.w + bv.w);
    if (gp0 + 1 < B)
        *(float4*)&out[(long long)(gp0 + 1) * 64 + tc * 4] =
            make_float4(a1.x + bv.x, a1.y + bv.y, a1.z + bv.z, a1.w + bv.w);
}

// Fused single-kernel MLP (used only if workspace can't hold H).
__global__ __launch_bounds__(256, 1) void mlp_fused(
    const float* __restrict__ feat,    // [B][64]
    const float* __restrict__ w1,      // [64][256]
    const float* __restrict__ b1,
    const float* __restrict__ w2,      // [256][64]
    const float* __restrict__ b2,
    float* __restrict__ out, int B)
{
    __shared__ float fsT[64][68];      // [k][p]
    __shared__ float w1s[64 * 256];    // 64 KB
    __shared__ float hT[256][65];
    int t = threadIdx.x;
    int p0 = blockIdx.x * MLP_P;

    {
        const float4* wg = (const float4*)w1;
        float4* wd = (float4*)w1s;
        #pragma unroll
        for (int r = 0; r < 16; ++r) wd[t + 256 * r] = wg[t + 256 * r];
    }
    #pragma unroll
    for (int r = 0; r < 16; ++r) {
        int idx = t + 256 * r;         // 64p x 64k
        int p = idx >> 6;
        int k = idx & 63;
        int gp = p0 + p;
        fsT[k][p] = (gp < B) ? feat[(long long)gp * 64 + k] : 0.f;
    }
    __syncthreads();

    {
        int tp = t >> 5;          // 0..7
        int to = t & 31;          // 0..31
        float acc[8][8];
        #pragma unroll
        for (int i = 0; i < 8; ++i)
            #pragma unroll
            for (int j = 0; j < 8; ++j) acc[i][j] = 0.f;

        #pragma unroll 4
        for (int k = 0; k < 64; ++k) {
            float4 fA = *(const float4*)&fsT[k][tp * 8];
            float4 fB = *(const float4*)&fsT[k][tp * 8 + 4];
            const float* wr = w1s + k * 256 + to;
            float w[8];
            #pragma unroll
            for (int j = 0; j < 8; ++j) w[j] = wr[32 * j];
            float f0 = fA.x, f1 = fA.y, f2 = fA.z, f3 = fA.w;
            float f4 = fB.x, f5 = fB.y, f6 = fB.z, f7 = fB.w;
            #pragma unroll
            for (int j = 0; j < 8; ++j) {
                acc[0][j] += f0 * w[j]; acc[1][j] += f1 * w[j];
                acc[2][j] += f2 * w[j]; acc[3][j] += f3 * w[j];
                acc[4][j] += f4 * w[j]; acc[5][j] += f5 * w[j];
                acc[6][j] += f6 * w[j]; acc[7][j] += f7 * w[j];
            }
        }
        #pragma unroll
        for (int j = 0; j < 8; ++j) {
            int o = to + 32 * j;
            float bb = b1[o];
            #pragma unroll
            for (int i = 0; i < 8; ++i)
                hT[o][tp * 8 + i] = fmaxf(acc[i][j] + bb, 0.f);
        }
    }
    __syncthreads();

    {
        int tp2 = t >> 4;
        int tc  = t & 15;
        float a0x = 0.f, a0y = 0.f, a0z = 0.f, a0w = 0.f;
        float a1x = 0.f, a1y = 0.f, a1z = 0.f, a1w = 0.f;
        float a2x = 0.f, a2y = 0.f, a2z = 0.f, a2w = 0.f;
        float a3x = 0.f, a3y = 0.f, a3z = 0.f, a3w = 0.f;

        #pragma unroll 8
        for (int k = 0; k < 256; ++k) {
            float h0 = hT[k][tp2 * 4 + 0];
            float h1 = hT[k][tp2 * 4 + 1];
            float h2 = hT[k][tp2 * 4 + 2];
            float h3 = hT[k][tp2 * 4 + 3];
            float4 wv = *(const float4*)&w2[k * 64 + tc * 4];
            a0x += h0 * wv.x; a0y += h0 * wv.y; a0z += h0 * wv.z; a0w += h0 * wv.w;
            a1x += h1 * wv.x; a1y += h1 * wv.y; a1z += h1 * wv.z; a1w += h1 * wv.w;
            a2x += h2 * wv.x; a2y += h2 * wv.y; a2z += h2 * wv.z; a2w += h2 * wv.w;
            a3x += h3 * wv.x; a3y += h3 * wv.y; a3z += h3 * wv.z; a3w += h3 * wv.w;
        }
        float4 bv = *(const float4*)&b2[tc * 4];
        int gp = p0 + tp2 * 4;
        float* op = out + (long long)gp * 64 + tc * 4;
        if (gp + 0 < B) *(float4*)(op + 0 * 64) =
            make_float4(a0x + bv.x, a0y + bv.y, a0z + bv.z, a0w + bv.w);
        if (gp + 1 < B) *(float4*)(op + 1 * 64) =
            make_float4(a1x + bv.x, a1y + bv.y, a1z + bv.z, a1w + bv.w);
        if (gp + 2 < B) *(float4*)(op + 2 * 64) =
            make_float4(a2x + bv.x, a2y + bv.y, a2z + bv.z, a2w + bv.w);
        if (gp + 3 < B) *(float4*)(op + 3 * 64) =
            make_float4(a3x + bv.x, a3y + bv.y, a3z + bv.z, a3w + bv.w);
    }
}

// ---------------- fallback (atomic) path ----------------

__global__ __launch_bounds__(256) void init_tables(
    const float* __restrict__ rp1, const float* __restrict__ rp2,
    const float* __restrict__ rp3, const float* __restrict__ times,
    const float* __restrict__ now_time, int E,
    float* __restrict__ new1, float* __restrict__ new2, float* __restrict__ new3,
    long long n4)
{
    float tlast = times[E - 1];
    float dec = expf(-WDECAY * (tlast - now_time[0]));
    float d2 = dec * dec;
    float d3 = d2 * dec;
    const float4* r1 = (const float4*)rp1;
    const float4* r2 = (const float4*)rp2;
    const float4* r3 = (const float4*)rp3;
    float4* n1 = (float4*)new1;
    float4* n2 = (float4*)new2;
    float4* n3 = (float4*)new3;
    long long i = (long long)blockIdx.x * blockDim.x + threadIdx.x;
    long long stride = (long long)gridDim.x * blockDim.x;
    for (; i < n4; i += stride) {
        float4 a = r1[i]; a.x *= dec; a.y *= dec; a.z *= dec; a.w *= dec; n1[i] = a;
        float4 b = r2[i]; b.x *= d2; b.y *= d2; b.z *= d2; b.w *= d2; n2[i] = b;
        float4 c = r3[i]; c.x *= d3; c.y *= d3; c.z *= d3; c.w *= d3; n3[i] = c;
    }
}

__global__ __launch_bounds__(256) void scatter_edges(
    const float* __restrict__ rp0, const float* __restrict__ rp1,
    const float* __restrict__ rp2, const float* __restrict__ times,
    const float* __restrict__ now_time,
    const int* __restrict__ src_ids, const int* __restrict__ dst_ids, int E,
    float* __restrict__ new1, float* __restrict__ new2, float* __restrict__ new3)
{
    int e = blockIdx.x;
    int d = threadIdx.x;
    float tlast = times[E - 1];
    float dec = expf(-WDECAY * (tlast - now_time[0]));
    float d2 = dec * dec;
    float tw = expf(-WDECAY * (tlast - times[e]));
    long long s = src_ids[e];
    long long t = dst_ids[e];
    long long so = s * D + d;
    long long to = t * D + d;
    float a0s = rp0[so], a0t = rp0[to];
    atomicAdd(&new1[so], a0t * tw);
    atomicAdd(&new1[to], a0s * tw);
    float a1s = rp1[so] * dec, a1t = rp1[to] * dec;
    atomicAdd(&new2[so], a1t * tw);
    atomicAdd(&new2[to], a1s * tw);
    float a2s = rp2[so] * d2, a2t = rp2[to] * d2;
    atomicAdd(&new3[so], a2t * tw);
    atomicAdd(&new3[to], a2s * tw);
}

__global__ __launch_bounds__(64) void pair_feature_mlp(
    const float* __restrict__ rp0, const float* __restrict__ new1,
    const float* __restrict__ new2, const float* __restrict__ new3,
    const int* __restrict__ q_src, const int* __restrict__ q_dst,
    const float* __restrict__ w1, const float* __restrict__ b1,
    const float* __restrict__ w2, const float* __restrict__ b2,
    float* __restrict__ out, int B)
{
    __shared__ float proj[8][260];
    __shared__ float feat_s[64];
    __shared__ float h_s[256];

    int b = blockIdx.x;
    int lid = threadIdx.x;
    long long qs = q_src[b];
    long long qd = q_dst[b];

    const float* tabs[4] = {rp0, new1, new2, new3};
    #pragma unroll
    for (int r = 0; r < 4; ++r) {
        const float* tp = tabs[r];
        float4 v = *(const float4*)(tp + qs * D + lid * 4);
        *(float4*)&proj[r][lid * 4] = v;
        float4 w = *(const float4*)(tp + qd * D + lid * 4);
        *(float4*)&proj[r + 4][lid * 4] = w;
    }
    __syncthreads();

    int p = lid >> 3;
    int q = lid & 7;
    float acc = 0.f;
    #pragma unroll 8
    for (int k = 0; k < 64; ++k) {
        float4 a = *(const float4*)&proj[p][4 * k];
        float4 c = *(const float4*)&proj[q][4 * k];
        acc += a.x * c.x + a.y * c.y + a.z * c.z + a.w * c.w;
    }
    feat_s[lid] = log1pf(fmaxf(acc, 0.f));
    __syncthreads();

    float4 hv = *(const float4*)(b1 + 4 * lid);
    #pragma unroll 4
    for (int i = 0; i < 64; ++i) {
        float fv = feat_s[i];
        float4 w = *(const float4*)(w1 + i * 256 + 4 * lid);
        hv.x += fv * w.x; hv.y += fv * w.y; hv.z += fv * w.z; hv.w += fv * w.w;
    }
    *(float4*)&h_s[4 * lid] = make_float4(fmaxf(hv.x, 0.f), fmaxf(hv.y, 0.f),
                                          fmaxf(hv.z, 0.f), fmaxf(hv.w, 0.f));
    __syncthreads();

    float o0 = 0.f, o1 = 0.f, o2 = 0.f, o3 = 0.f;
    #pragma unroll 4
    for (int j = 0; j < 256; j += 4) {
        o0 += h_s[j + 0] * w2[(j + 0) * 64 + lid];
        o1 += h_s[j + 1] * w2[(j + 1) * 64 + lid];
        o2 += h_s[j + 2] * w2[(j + 2) * 64 + lid];
        o3 += h_s[j + 3] * w2[(j + 3) * 64 + lid];
    }
    out[(long long)b * 64 + lid] = b2[lid] + (o0 + o1) + (o2 + o3);
}

extern "C" void kernel_launch(void* const* d_in, const int* in_sizes, int n_in,
                              void* d_out, int out_size, void* d_ws, size_t ws_size,
                              hipStream_t stream)
{
    const float* rp0      = (const float*)d_in[0];
    const float* rp1      = (const float*)d_in[1];
    const float* rp2      = (const float*)d_in[2];
    const float* rp3      = (const float*)d_in[3];
    const float* times    = (const float*)d_in[4];
    const float* now_time = (const float*)d_in[5];
    const float* w1       = (const float*)d_in[6];
    const float* b1       = (const float*)d_in[7];
    const float* w2       = (const float*)d_in[8];
    const float* b2       = (const float*)d_in[9];
    const int*   src_ids  = (const int*)d_in[10];
    const int*   dst_ids  = (const int*)d_in[11];
    const int*   q_src    = (const int*)d_in[12];
    const int*   q_dst    = (const int*)d_in[13];
    float* out = (float*)d_out;

    long long ND = in_sizes[0];      // N * D
    int N = (int)(ND / D);
    int E = in_sizes[4];
    int B = in_sizes[12];
    int NB = (N + CHUNK - 1) / CHUNK;

    float* new1 = (float*)d_ws;
    float* new2 = new1 + ND;
    float* new3 = new2 + ND;

    size_t base_bytes = (size_t)3 * ND * sizeof(float);
    size_t csr_bytes  = (size_t)(2 * N + (N + 1) + 2 * E + NB) * sizeof(int)
                      + (size_t)(2 * E) * sizeof(float)
                      + (size_t)B * 64 * sizeof(float);
    size_t h_bytes    = (size_t)B * 256 * sizeof(float);

    if (ws_size >= base_bytes + csr_bytes && NB <= 65536) {
        int* cnt       = (int*)(new3 + ND);           // N (becomes cursor)
        int* flag      = cnt + N;                     // N
        int* row_start = flag + N;                    // N+1
        int* adj_other = row_start + N + 1;           // 2E
        float* adj_tw  = (float*)(adj_other + 2 * E); // 2E
        int* bsum      = (int*)(adj_tw + 2 * E);      // NB
        float* feat    = (float*)(bsum + NB);         // B*64
        float* Hbuf    = feat + (size_t)B * 64;       // B*256 (if it fits)
        bool   split   = (ws_size >= base_bytes + csr_bytes + h_bytes);

        hipMemsetAsync(cnt, 0, (size_t)2 * N * sizeof(int), stream);  // cnt + flag
        int twoE = 2 * E;
        hist_kernel<<<(twoE + 255) / 256, 256, 0, stream>>>(src_ids, dst_ids, E, cnt);
        set_flags<<<(B + 255) / 256, 256, 0, stream>>>(q_src, q_dst, B, flag);
        scan_partial<<<NB, 256, 0, stream>>>(cnt, N, bsum);
        scan_blocksums<<<1, 256, 0, stream>>>(bsum, NB, row_start, N);
        scan_apply<<<NB, 256, 0, stream>>>(cnt, bsum, row_start, N);
        fill_kernel<<<(twoE + 255) / 256, 256, 0, stream>>>(src_ids, dst_ids, times, E,
                                                            cnt, adj_other, adj_tw);
        dim3 grid(N, 3);
        apply_updates<<<grid, 64, 0, stream>>>(rp0, rp1, rp2, rp3, times, now_time, E,
                                               row_start, adj_other, adj_tw, flag,
                                               new1, new2, new3);
        gather_gram<<<(B + 3) / 4, 256, 0, stream>>>(rp0, new1, new2, new3,
                                                     q_src, q_dst, feat, B);
        if (split) {
            mlp1_kernel<<<(B + P1 - 1) / P1, 256, 0, stream>>>(feat, w1, b1, Hbuf, B);
            mlp2_kernel<<<(B + P2 - 1) / P2, 256, 0, stream>>>(Hbuf, w2, b2, out, B);
        } else {
            mlp_fused<<<(B + MLP_P - 1) / MLP_P, 256, 0, stream>>>(feat, w1, b1, w2, b2,
                                                                   out, B);
        }
    } else {
        long long n4 = ND / 4;
        init_tables<<<2048, 256, 0, stream>>>(rp1, rp2, rp3, times, now_time, E,
                                              new1, new2, new3, n4);
        scatter_edges<<<E, 256, 0, stream>>>(rp0, rp1, rp2, times, now_time,
                                             src_ids, dst_ids, E, new1, new2, new3);
        pair_feature_mlp<<<B, 64, 0, stream>>>(rp0, new1, new2, new3, q_src, q_dst,
                                               w1, b1, w2, b2, out, B);
    }
}